// Round 14
// baseline (1105.386 us; speedup 1.0000x reference)
//
#include <hip/hip_runtime.h>
#include <hip/hip_bf16.h>

#define NWORDS 8192
#define LW 24
#define DIM 256
#define NHEAD 8
#define DFF 1024
#define NCONC 1024
#define MAXW 16
#define TN (NCONC * MAXW)          // 16384 name tokens

typedef float floatx4 __attribute__((ext_vector_type(4)));
typedef short shortx8 __attribute__((ext_vector_type(8)));

__device__ __forceinline__ float bf2f(ushort u) {
  union { uint u; float f; } v; v.u = ((uint)u) << 16; return v.f;
}
__device__ __forceinline__ ushort f2bf(float f) {
  union { float f; uint u; } v; v.f = f;
  return (ushort)((v.u + 0x7FFFu + ((v.u >> 16) & 1u)) >> 16);
}

// async global->LDS, 16B per lane; LDS dst is wave-uniform base + lane*16
__device__ __forceinline__ void load_lds16(const ushort* gsrc, ushort* lds) {
  __builtin_amdgcn_global_load_lds((const __attribute__((address_space(1))) void*)gsrc,
                                   (__attribute__((address_space(3))) void*)lds, 16, 0, 0);
}

// s_waitcnt imm: vmcnt[3:0]=b3:0,[5:4]=b15:14; expcnt=b6:4; lgkmcnt=b11:8
#define WAIT_VM0() __builtin_amdgcn_s_waitcnt(0x0F70)    // vmcnt(0), others max
#define WAIT_LGKM0() __builtin_amdgcn_s_waitcnt(0xC07F)  // lgkmcnt(0), others max

// Swizzled LDS tile (R6-verified: SQ_LDS_BANK_CONFLICT == 0): rows of 32 ushort
// (64B) in 4 16B chunks; chunk c of row r stored at slot c ^ ((r>>1)&3).
#define STAGE_COL(lane) ((((lane) & 3) ^ (((lane) >> 3) & 3)) * 8)
#define FRAG_OFF(row, quad) (((row) * 32) + ((((quad) ^ (((row) >> 1) & 3))) * 8))

// ---------------- weight transpose + cast: W[K x N] f32 -> WT[N x K] bf16
__global__ __launch_bounds__(256) void wprep(const float* __restrict__ W,
                                             ushort* __restrict__ WT, int K, int N) {
  int idx = blockIdx.x * 256 + threadIdx.x;
  if (idx < K * N) {
    int k = idx / N, n = idx % N;
    WT[n * K + k] = f2bf(W[idx]);
  }
}

// ---------------- embedding gather -> bf16 x (vectorized: 1 thread = 4 elems)
__global__ __launch_bounds__(256) void embed4(const int* __restrict__ inputs,
                                              const float* __restrict__ we_emb,
                                              ushort* __restrict__ x, int ntok) {
  int idx = blockIdx.x * 256 + threadIdx.x;
  int t = idx >> 6, d = (idx & 63) * 4;
  if (t < ntok) {
    const float4 f = *(const float4*)&we_emb[inputs[t] * DIM + d];
    uint2 o;
    o.x = (uint)f2bf(f.x) | ((uint)f2bf(f.y) << 16);
    o.y = (uint)f2bf(f.z) | ((uint)f2bf(f.w) << 16);
    *(uint2*)&x[(size_t)t * DIM + d] = o;
  }
}

// ---------------- GEMM, K=256 fixed, 64 tokens/block, N-tile 256 per block
// (R0-proven config: 4 waves / 256 thr; wave owns 64 cols; barrier-free K-loop)
// R14: RELU template param (ff1 path: S = relu(h W1), plain store).
template <bool LN, bool RELU>
__global__ __launch_bounds__(256, 2) void gemm_tok64(const ushort* __restrict__ A, int lda,
                                                     const ushort* __restrict__ BT,  // [N x 256]
                                                     const ushort* __restrict__ RES, // [M x 256] | null
                                                     ushort* __restrict__ C, int ldc) {
  __shared__ __align__(16) ushort As[8 * 64 * 32];  // tokens: 8 k-planes x 64 rows (32 KB)
  __shared__ __align__(16) ushort Wb[256 * 32];     // weight plane; wave w owns rows w*64.. (16 KB)
  __shared__ float red1[64 * 4];
  __shared__ float red2[64 * 4];
  const int tid = threadIdx.x;
  const int w = tid >> 6, lane = tid & 63;
  const int quad = lane >> 4, l16 = lane & 15;
  const long m0 = (long)blockIdx.y * 64;
  const long nb = (long)blockIdx.x * 256;           // N-tile base
  const int srow = lane >> 2;
  const int scol = STAGE_COL(lane);
  const int wc = w * 64;

  // stage A tile once: 8 planes x 4 row-groups = 32 insts, 8 per wave
#pragma unroll
  for (int t = 0; t < 8; t++) {
    int p = 2 * w + t / 4, ii = t % 4;
    load_lds16(&A[(m0 + ii * 16 + srow) * lda + p * 32 + scol], &As[p * 2048 + (ii * 16) * 32]);
  }
  // prestage weight plane 0 (wave's own quarter)
#pragma unroll
  for (int ii = 0; ii < 4; ii++)
    load_lds16(&BT[(nb + wc + ii * 16 + srow) * 256 + scol], &Wb[(wc + ii * 16) * 32]);
  __syncthreads();   // As (cross-wave) + own Wb plane 0 ready

  floatx4 acc[4][4] = {};
#pragma unroll 1
  for (int p = 0; p < 8; p++) {        // K plane — per-wave fences, no barriers
    WAIT_VM0();                        // own staged plane landed
    shortx8 a[4], b[4];
#pragma unroll
    for (int j = 0; j < 4; j++)
      b[j] = *(const shortx8*)&Wb[FRAG_OFF(wc + j * 16 + l16, quad)];
    WAIT_LGKM0();                      // frags in VGPRs; Wb quarter reusable
    if (p < 7) {
#pragma unroll
      for (int ii = 0; ii < 4; ii++)
        load_lds16(&BT[(nb + wc + ii * 16 + srow) * 256 + (p + 1) * 32 + scol],
                   &Wb[(wc + ii * 16) * 32]);
    }
#pragma unroll
    for (int i = 0; i < 4; i++)
      a[i] = *(const shortx8*)&As[p * 2048 + FRAG_OFF(i * 16 + l16, quad)];
#pragma unroll
    for (int i = 0; i < 4; i++)
#pragma unroll
      for (int j = 0; j < 4; j++)
        acc[i][j] = __builtin_amdgcn_mfma_f32_16x16x32_bf16(a[i], b[j], acc[i][j], 0, 0, 0);
  }

  if (!LN) {
    // plain store (QKV / ff1); optional relu
#pragma unroll
    for (int i = 0; i < 4; i++)
#pragma unroll
      for (int j = 0; j < 4; j++)
#pragma unroll
        for (int r = 0; r < 4; r++) {
          long m = m0 + i * 16 + quad * 4 + r;
          float v = acc[i][j][r];
          if (RELU) v = fmaxf(v, 0.f);
          C[m * ldc + nb + wc + j * 16 + l16] = f2bf(v);
        }
    return;
  }

  // residual + LN epilogue (N==256, gridDim.x==1 -> nb==0)
#pragma unroll
  for (int i = 0; i < 4; i++)
#pragma unroll
    for (int r = 0; r < 4; r++) {
      int row = i * 16 + quad * 4 + r;
      float s1 = 0.f, s2 = 0.f;
#pragma unroll
      for (int j = 0; j < 4; j++) {
        float v = acc[i][j][r] + bf2f(RES[(m0 + row) * 256 + wc + j * 16 + l16]);
        acc[i][j][r] = v;
        s1 += v;
        s2 += v * v;
      }
#pragma unroll
      for (int off = 1; off < 16; off <<= 1) {
        s1 += __shfl_xor(s1, off);
        s2 += __shfl_xor(s2, off);
      }
      if (l16 == 0) { red1[row * 4 + w] = s1; red2[row * 4 + w] = s2; }
    }
  __syncthreads();
#pragma unroll
  for (int i = 0; i < 4; i++)
#pragma unroll
    for (int r = 0; r < 4; r++) {
      int row = i * 16 + quad * 4 + r;
      float s1 = red1[row * 4] + red1[row * 4 + 1] + red1[row * 4 + 2] + red1[row * 4 + 3];
      float s2 = red2[row * 4] + red2[row * 4 + 1] + red2[row * 4 + 2] + red2[row * 4 + 3];
      float mean = s1 * (1.f / 256.f);
      float rstd = rsqrtf(s2 * (1.f / 256.f) - mean * mean + 1e-5f);
#pragma unroll
      for (int j = 0; j < 4; j++)
        C[(m0 + row) * 256 + wc + j * 16 + l16] = f2bf((acc[i][j][r] - mean) * rstd);
    }
}

// ---------------- ff2: C = LN(RES + S W2), K=1024 via 4 chunks of 256.
// Same proven barrier-free plane loop; As restaged per K-chunk (2 barriers
// per chunk, 8 per block — vs 12 in the retired fused kernel).  N=256.
__global__ __launch_bounds__(256, 2) void gemm_k1024_ln(const ushort* __restrict__ A,   // [M x 1024] = S
                                                        const ushort* __restrict__ BT,  // [256 x 1024] = W2T
                                                        const ushort* __restrict__ RES, // [M x 256]
                                                        ushort* __restrict__ C) {       // [M x 256]
  __shared__ __align__(16) ushort As[8 * 64 * 32];  // 8 k-planes x 64 rows (32 KB)
  __shared__ __align__(16) ushort Wb[256 * 32];     // weight plane; wave w owns rows w*64.. (16 KB)
  __shared__ float red1[64 * 4];
  __shared__ float red2[64 * 4];
  const int tid = threadIdx.x;
  const int w = tid >> 6, lane = tid & 63;
  const int quad = lane >> 4, l16 = lane & 15;
  const long m0 = (long)blockIdx.x * 64;
  const int srow = lane >> 2;
  const int scol = STAGE_COL(lane);
  const int wc = w * 64;

  floatx4 acc[4][4] = {};
#pragma unroll 1
  for (int kc = 0; kc < 4; kc++) {     // K-chunk of 256
    // stage As chunk: 8 planes x 4 row-groups = 32 insts, 8 per wave
#pragma unroll
    for (int t = 0; t < 8; t++) {
      int p = 2 * w + t / 4, ii = t % 4;
      load_lds16(&A[(m0 + ii * 16 + srow) * 1024 + kc * 256 + p * 32 + scol],
                 &As[p * 2048 + (ii * 16) * 32]);
    }
    // prestage weight plane 0 of this chunk (wave's own quarter)
#pragma unroll
    for (int ii = 0; ii < 4; ii++)
      load_lds16(&BT[(long)(wc + ii * 16 + srow) * 1024 + kc * 256 + scol],
                 &Wb[(wc + ii * 16) * 32]);
    __syncthreads();   // As (cross-wave) + own Wb plane 0 ready

#pragma unroll 1
    for (int p = 0; p < 8; p++) {      // plane loop — per-wave fences, no barriers
      WAIT_VM0();
      shortx8 a[4], b[4];
#pragma unroll
      for (int j = 0; j < 4; j++)
        b[j] = *(const shortx8*)&Wb[FRAG_OFF(wc + j * 16 + l16, quad)];
      WAIT_LGKM0();
      if (p < 7) {
#pragma unroll
        for (int ii = 0; ii < 4; ii++)
          load_lds16(&BT[(long)(wc + ii * 16 + srow) * 1024 + kc * 256 + (p + 1) * 32 + scol],
                     &Wb[(wc + ii * 16) * 32]);
      }
#pragma unroll
      for (int i = 0; i < 4; i++)
        a[i] = *(const shortx8*)&As[p * 2048 + FRAG_OFF(i * 16 + l16, quad)];
#pragma unroll
      for (int i = 0; i < 4; i++)
#pragma unroll
        for (int j = 0; j < 4; j++)
          acc[i][j] = __builtin_amdgcn_mfma_f32_16x16x32_bf16(a[i], b[j], acc[i][j], 0, 0, 0);
    }
    __syncthreads();   // all waves done with As before next chunk overwrites it
  }

  // residual + LN epilogue
#pragma unroll
  for (int i = 0; i < 4; i++)
#pragma unroll
    for (int r = 0; r < 4; r++) {
      int row = i * 16 + quad * 4 + r;
      float s1 = 0.f, s2 = 0.f;
#pragma unroll
      for (int j = 0; j < 4; j++) {
        float v = acc[i][j][r] + bf2f(RES[(m0 + row) * 256 + wc + j * 16 + l16]);
        acc[i][j][r] = v;
        s1 += v;
        s2 += v * v;
      }
#pragma unroll
      for (int off = 1; off < 16; off <<= 1) {
        s1 += __shfl_xor(s1, off);
        s2 += __shfl_xor(s2, off);
      }
      if (l16 == 0) { red1[row * 4 + w] = s1; red2[row * 4 + w] = s2; }
    }
  __syncthreads();
#pragma unroll
  for (int i = 0; i < 4; i++)
#pragma unroll
    for (int r = 0; r < 4; r++) {
      int row = i * 16 + quad * 4 + r;
      float s1 = red1[row * 4] + red1[row * 4 + 1] + red1[row * 4 + 2] + red1[row * 4 + 3];
      float s2 = red2[row * 4] + red2[row * 4 + 1] + red2[row * 4 + 2] + red2[row * 4 + 3];
      float mean = s1 * (1.f / 256.f);
      float rstd = rsqrtf(s2 * (1.f / 256.f) - mean * mean + 1e-5f);
#pragma unroll
      for (int j = 0; j < 4; j++)
        C[(m0 + row) * 256 + wc + j * 16 + l16] = f2bf((acc[i][j][r] - mean) * rstd);
    }
}

// ---------------- attention per sequence; o overwrites the q slot of qkv
template <int LSEQ, bool MASKED>
__global__ __launch_bounds__(256) void attn(const int* __restrict__ inputs,
                                            ushort* __restrict__ qkv) {
  __shared__ ushort Qs[LSEQ * 256];
  __shared__ ushort Ks[LSEQ * 256];
  __shared__ ushort Vs[LSEQ * 256];
  __shared__ float pads[LSEQ];
  const int blk = blockIdx.x;
  const int tid = threadIdx.x;
  ushort* base = qkv + (size_t)blk * LSEQ * 768;
  const uint4* src = (const uint4*)base;
  for (int i = tid; i < LSEQ * 96; i += 256) {
    int c = i / 96, part = i % 96;
    uint4 val = src[c * 96 + part];
    int sect = part >> 5, off = part & 31;
    ushort* dst = (sect == 0) ? Qs : (sect == 1 ? Ks : Vs);
    *(uint4*)&dst[c * 256 + off * 8] = val;
  }
  if (MASKED) {
    if (tid < LSEQ) pads[tid] = (inputs[blk * LSEQ + tid] == 0) ? 1.f : 0.f;
  }
  __syncthreads();
  if (tid < LSEQ * NHEAD) {
    const int i = tid % LSEQ, hh = tid / LSEQ;
    const int hb = hh * 32;
    float q[32];
    {
      const uint4* qr = (const uint4*)&Qs[i * 256 + hb];
#pragma unroll
      for (int u = 0; u < 4; u++) {
        uint4 ch = qr[u];
        const ushort* us = (const ushort*)&ch;
#pragma unroll
        for (int d = 0; d < 8; d++) q[u * 8 + d] = bf2f(us[d]);
      }
    }
    float s[LSEQ];
    float mx = -3e38f;
#pragma unroll
    for (int j = 0; j < LSEQ; j++) {
      const uint4* kr = (const uint4*)&Ks[j * 256 + hb];
      float a = 0.f;
#pragma unroll
      for (int u = 0; u < 4; u++) {
        uint4 ch = kr[u];
        const ushort* us = (const ushort*)&ch;
#pragma unroll
        for (int d = 0; d < 8; d++) a += q[u * 8 + d] * bf2f(us[d]);
      }
      a *= 0.17677669529663687f;
      if (MASKED && pads[j] != 0.f) a = -1e9f;
      s[j] = a;
      mx = fmaxf(mx, a);
    }
    float den = 0.f;
#pragma unroll
    for (int j = 0; j < LSEQ; j++) { s[j] = __expf(s[j] - mx); den += s[j]; }
    float inv = 1.f / den;
    float o[32] = {};
#pragma unroll
    for (int j = 0; j < LSEQ; j++) {
      float a = s[j] * inv;
      const uint4* vr = (const uint4*)&Vs[j * 256 + hb];
#pragma unroll
      for (int u = 0; u < 4; u++) {
        uint4 ch = vr[u];
        const ushort* us = (const ushort*)&ch;
#pragma unroll
        for (int d = 0; d < 8; d++) o[u * 8 + d] += a * bf2f(us[d]);
      }
    }
    ushort* orow = base + (size_t)i * 768 + hb;
#pragma unroll
    for (int d = 0; d < 32; d++) orow[d] = f2bf(o[d]);
  }
}

// ---------------- masked mean over chars -> scatter into padded + flag real slots
__global__ __launch_bounds__(256) void pool_scatter(const ushort* __restrict__ ft,
                                                    const int* __restrict__ inputs,
                                                    const int* __restrict__ cid,
                                                    const int* __restrict__ wpos,
                                                    ushort* __restrict__ padded,
                                                    int* __restrict__ flags) {
  int w = blockIdx.x, d = threadIdx.x;
  float s = 0.f;
  int cnt = 0;
  for (int c = 0; c < LW; c++) {
    if (inputs[w * LW + c] != 0) {
      s += bf2f(ft[((size_t)w * LW + c) * DIM + d]);
      cnt++;
    }
  }
  int slot = cid[w] * MAXW + wpos[w];
  padded[(size_t)slot * DIM + d] = f2bf(s / (float)cnt);
  if (d == 0) flags[slot] = 1;
}

// ---------------- final: mean over real word rows per concept -> f32 out
__global__ __launch_bounds__(256) void final_pool(const ushort* __restrict__ nft,
                                                  const int* __restrict__ flags,
                                                  float* __restrict__ out) {
  int n = blockIdx.x, d = threadIdx.x;
  float s = 0.f;
  int cnt = 0;
  for (int wd = 0; wd < MAXW; wd++) {
    if (flags[n * MAXW + wd]) {
      s += bf2f(nft[((size_t)n * MAXW + wd) * DIM + d]);
      cnt++;
    }
  }
  out[n * DIM + d] = s / (float)cnt;
}

extern "C" void kernel_launch(void* const* d_in, const int* in_sizes, int n_in,
                              void* d_out, int out_size, void* d_ws, size_t ws_size,
                              hipStream_t stream) {
  const int* inputs = (const int*)d_in[0];
  const int* cid = (const int*)d_in[1];
  const int* wpos = (const int*)d_in[2];
  const float* we_emb = (const float*)d_in[5];
  const float* we_qkv = (const float*)d_in[6];
  const float* we_o = (const float*)d_in[7];
  const float* we_ff1 = (const float*)d_in[8];
  const float* we_ff2 = (const float*)d_in[9];
  const float* ne_qkv = (const float*)d_in[10];
  const float* ne_o = (const float*)d_in[11];
  const float* ne_ff1 = (const float*)d_in[12];
  const float* ne_ff2 = (const float*)d_in[13];
  float* out = (float*)d_out;

  int chunks = 4;
  if (ws_size >= 515000000UL) chunks = 1;
  else if (ws_size >= 263258112UL) chunks = 2;
  const int wpc = NWORDS / chunks;
  const int tpc = wpc * LW;

  const size_t X = (size_t)tpc * DIM * 2;      // x / h size
  const size_t Q = (size_t)tpc * 768 * 2;      // qkv size

  char* base = (char*)d_ws;
  ushort* x = (ushort*)(base);
  ushort* qkv = (ushort*)(base + X);
  ushort* h = (ushort*)(base + X + Q);
  ushort* ft = qkv;                             // qkv dead after o-proj; ft = first X of it
  ushort* S = (ushort*)(base + 2 * X);          // ff1 output (half-chunk), spans 2X, ends at X+Q
  size_t pend = X + Q + X;
  ushort* padded = (ushort*)(base + pend);                // 8,388,608 B
  int* flags = (int*)(base + pend + 8388608);             // 65,536 B
  ushort* wT = (ushort*)(base + pend + 8454144);          // 3,145,728 B
  // name-stage buffers alias the word-stage region (dead by then)
  ushort* nqkv = (ushort*)(base);                         // 25,165,824
  ushort* nh = (ushort*)(base + 25165824);                // 8,388,608
  ushort* nft = (ushort*)(base + 33554432);               // 8,388,608
  ushort* Sn = (ushort*)(base + 41943040);                // 33,554,432 (name ff1 out)

  ushort* wqkvT = wT;
  ushort* woT = wT + 196608;
  ushort* wff1T = wT + 262144;
  ushort* wff2T = wT + 524288;
  ushort* nqkvT = wT + 786432;
  ushort* neoT = wT + 983040;
  ushort* neff1T = wT + 1048576;
  ushort* neff2T = wT + 1310720;

  wprep<<<768, 256, 0, stream>>>(we_qkv, wqkvT, 256, 768);
  wprep<<<256, 256, 0, stream>>>(we_o, woT, 256, 256);
  wprep<<<1024, 256, 0, stream>>>(we_ff1, wff1T, 256, 1024);
  wprep<<<1024, 256, 0, stream>>>(we_ff2, wff2T, 1024, 256);
  wprep<<<768, 256, 0, stream>>>(ne_qkv, nqkvT, 256, 768);
  wprep<<<256, 256, 0, stream>>>(ne_o, neoT, 256, 256);
  wprep<<<1024, 256, 0, stream>>>(ne_ff1, neff1T, 256, 1024);
  wprep<<<1024, 256, 0, stream>>>(ne_ff2, neff2T, 1024, 256);

  (void)hipMemsetAsync(padded, 0, (size_t)TN * DIM * 2, stream);
  (void)hipMemsetAsync(flags, 0, TN * 4, stream);

  for (int c = 0; c < chunks; c++) {
    const int* in_c = inputs + (size_t)c * wpc * LW;
    const int* cid_c = cid + (size_t)c * wpc;
    const int* wpos_c = wpos + (size_t)c * wpc;

    embed4<<<tpc / 4, 256, 0, stream>>>(in_c, we_emb, x, tpc);
    // QKV: 3 N-tiles of 256 over the 768-wide output (blockIdx.x = N-tile)
    {
      dim3 g(3, tpc / 64);
      gemm_tok64<false, false><<<g, 256, 0, stream>>>(x, 256, wqkvT, nullptr, qkv, 768);
    }
    attn<24, true><<<wpc, 256, 0, stream>>>(in_c, qkv);
    // o-proj + residual(x) + LN -> h   (o lives in the q slot of qkv, lda=768)
    {
      dim3 g(1, tpc / 64);
      gemm_tok64<true, false><<<g, 256, 0, stream>>>(qkv, 768, woT, x, h, 256);
    }
    // FFN: two half-token passes so S (ldc=1024) fits the dead qkv region
    const int mh = tpc / 2;
    for (int half = 0; half < 2; half++) {
      const ushort* hh = h + (size_t)half * mh * 256;
      ushort* fth = ft + (size_t)half * mh * 256;
      {
        dim3 g(4, mh / 64);   // S = relu(h W1), N=1024
        gemm_tok64<false, true><<<g, 256, 0, stream>>>(hh, 256, wff1T, nullptr, S, 1024);
      }
      gemm_k1024_ln<<<mh / 64, 256, 0, stream>>>(S, wff2T, hh, fth);
    }
    pool_scatter<<<wpc, 256, 0, stream>>>(ft, in_c, cid_c, wpos_c, padded, flags);
  }

  // name-level block
  {
    dim3 g(3, TN / 64);
    gemm_tok64<false, false><<<g, 256, 0, stream>>>(padded, 256, nqkvT, nullptr, nqkv, 768);
  }
  attn<16, false><<<NCONC, 256, 0, stream>>>(nullptr, nqkv);
  {
    dim3 g(1, TN / 64);
    gemm_tok64<true, false><<<g, 256, 0, stream>>>(nqkv, 768, neoT, padded, nh, 256);
  }
  {
    dim3 g(4, TN / 64);   // Sn = relu(nh W1)
    gemm_tok64<false, true><<<g, 256, 0, stream>>>(nh, 256, neff1T, nullptr, Sn, 1024);
  }
  gemm_k1024_ln<<<TN / 64, 256, 0, stream>>>(Sn, neff2T, nh, nft);
  final_pool<<<NCONC, 256, 0, stream>>>(nft, flags, out);
}

// Round 15
// 936.346 us; speedup vs baseline: 1.1805x; 1.1805x over previous
//
#include <hip/hip_runtime.h>
#include <hip/hip_bf16.h>

#define NWORDS 8192
#define LW 24
#define DIM 256
#define NHEAD 8
#define DFF 1024
#define NCONC 1024
#define MAXW 16
#define TN (NCONC * MAXW)          // 16384 name tokens

typedef float floatx4 __attribute__((ext_vector_type(4)));
typedef short shortx8 __attribute__((ext_vector_type(8)));

__device__ __forceinline__ float bf2f(ushort u) {
  union { uint u; float f; } v; v.u = ((uint)u) << 16; return v.f;
}
__device__ __forceinline__ ushort f2bf(float f) {
  union { float f; uint u; } v; v.f = f;
  return (ushort)((v.u + 0x7FFFu + ((v.u >> 16) & 1u)) >> 16);
}

// async global->LDS, 16B per lane; LDS dst is wave-uniform base + lane*16
__device__ __forceinline__ void load_lds16(const ushort* gsrc, ushort* lds) {
  __builtin_amdgcn_global_load_lds((const __attribute__((address_space(1))) void*)gsrc,
                                   (__attribute__((address_space(3))) void*)lds, 16, 0, 0);
}

// s_waitcnt imm: vmcnt[3:0]=b3:0,[5:4]=b15:14; expcnt=b6:4; lgkmcnt=b11:8
#define WAIT_VM0() __builtin_amdgcn_s_waitcnt(0x0F70)    // vmcnt(0), others max
#define WAIT_LGKM0() __builtin_amdgcn_s_waitcnt(0xC07F)  // lgkmcnt(0), others max

// Swizzled LDS tile (R6-verified: SQ_LDS_BANK_CONFLICT == 0): rows of 32 ushort
// (64B) in 4 16B chunks; chunk c of row r stored at slot c ^ ((r>>1)&3).
#define STAGE_COL(lane) ((((lane) & 3) ^ (((lane) >> 3) & 3)) * 8)
#define FRAG_OFF(row, quad) (((row) * 32) + ((((quad) ^ (((row) >> 1) & 3))) * 8))

// ---------------- weight transpose + cast: W[K x N] f32 -> WT[N x K] bf16
__global__ __launch_bounds__(256) void wprep(const float* __restrict__ W,
                                             ushort* __restrict__ WT, int K, int N) {
  int idx = blockIdx.x * 256 + threadIdx.x;
  if (idx < K * N) {
    int k = idx / N, n = idx % N;
    WT[n * K + k] = f2bf(W[idx]);
  }
}

// ---------------- embedding gather -> bf16 x (vectorized: 1 thread = 4 elems)
__global__ __launch_bounds__(256) void embed4(const int* __restrict__ inputs,
                                              const float* __restrict__ we_emb,
                                              ushort* __restrict__ x, int ntok) {
  int idx = blockIdx.x * 256 + threadIdx.x;
  int t = idx >> 6, d = (idx & 63) * 4;
  if (t < ntok) {
    const float4 f = *(const float4*)&we_emb[inputs[t] * DIM + d];
    uint2 o;
    o.x = (uint)f2bf(f.x) | ((uint)f2bf(f.y) << 16);
    o.y = (uint)f2bf(f.z) | ((uint)f2bf(f.w) << 16);
    *(uint2*)&x[(size_t)t * DIM + d] = o;
  }
}

// ---------------- GEMM, K=256 fixed, 64 tokens/block, N-tile 256 per block
// (R0-proven config: 4 waves / 256 thr; wave owns 64 cols; barrier-free K-loop)
template <bool LN>
__global__ __launch_bounds__(256, 2) void gemm_tok64(const ushort* __restrict__ A, int lda,
                                                     const ushort* __restrict__ BT,  // [N x 256]
                                                     const ushort* __restrict__ RES, // [M x 256] | null
                                                     ushort* __restrict__ C, int ldc) {
  __shared__ __align__(16) ushort As[8 * 64 * 32];  // tokens: 8 k-planes x 64 rows (32 KB)
  __shared__ __align__(16) ushort Wb[256 * 32];     // weight plane; wave w owns rows w*64.. (16 KB)
  __shared__ float red1[64 * 4];
  __shared__ float red2[64 * 4];
  const int tid = threadIdx.x;
  const int w = tid >> 6, lane = tid & 63;
  const int quad = lane >> 4, l16 = lane & 15;
  const long m0 = (long)blockIdx.y * 64;
  const long nb = (long)blockIdx.x * 256;           // N-tile base
  const int srow = lane >> 2;
  const int scol = STAGE_COL(lane);
  const int wc = w * 64;

  // stage A tile once: 8 planes x 4 row-groups = 32 insts, 8 per wave
#pragma unroll
  for (int t = 0; t < 8; t++) {
    int p = 2 * w + t / 4, ii = t % 4;
    load_lds16(&A[(m0 + ii * 16 + srow) * lda + p * 32 + scol], &As[p * 2048 + (ii * 16) * 32]);
  }
  // prestage weight plane 0 (wave's own quarter)
#pragma unroll
  for (int ii = 0; ii < 4; ii++)
    load_lds16(&BT[(nb + wc + ii * 16 + srow) * 256 + scol], &Wb[(wc + ii * 16) * 32]);
  __syncthreads();   // As (cross-wave) + own Wb plane 0 ready

  floatx4 acc[4][4] = {};
#pragma unroll 1
  for (int p = 0; p < 8; p++) {        // K plane — per-wave fences, no barriers
    WAIT_VM0();                        // own staged plane landed
    shortx8 a[4], b[4];
#pragma unroll
    for (int j = 0; j < 4; j++)
      b[j] = *(const shortx8*)&Wb[FRAG_OFF(wc + j * 16 + l16, quad)];
    WAIT_LGKM0();                      // frags in VGPRs; Wb quarter reusable
    if (p < 7) {
#pragma unroll
      for (int ii = 0; ii < 4; ii++)
        load_lds16(&BT[(nb + wc + ii * 16 + srow) * 256 + (p + 1) * 32 + scol],
                   &Wb[(wc + ii * 16) * 32]);
    }
#pragma unroll
    for (int i = 0; i < 4; i++)
      a[i] = *(const shortx8*)&As[p * 2048 + FRAG_OFF(i * 16 + l16, quad)];
#pragma unroll
    for (int i = 0; i < 4; i++)
#pragma unroll
      for (int j = 0; j < 4; j++)
        acc[i][j] = __builtin_amdgcn_mfma_f32_16x16x32_bf16(a[i], b[j], acc[i][j], 0, 0, 0);
  }

  if (!LN) {
    // plain store (used for QKV; C is the 768-wide qkv buffer)
#pragma unroll
    for (int i = 0; i < 4; i++)
#pragma unroll
      for (int j = 0; j < 4; j++)
#pragma unroll
        for (int r = 0; r < 4; r++) {
          long m = m0 + i * 16 + quad * 4 + r;
          C[m * ldc + nb + wc + j * 16 + l16] = f2bf(acc[i][j][r]);
        }
    return;
  }

  // residual + LN epilogue (N==256, gridDim.x==1 -> nb==0)
#pragma unroll
  for (int i = 0; i < 4; i++)
#pragma unroll
    for (int r = 0; r < 4; r++) {
      int row = i * 16 + quad * 4 + r;
      float s1 = 0.f, s2 = 0.f;
#pragma unroll
      for (int j = 0; j < 4; j++) {
        float v = acc[i][j][r] + bf2f(RES[(m0 + row) * 256 + wc + j * 16 + l16]);
        acc[i][j][r] = v;
        s1 += v;
        s2 += v * v;
      }
#pragma unroll
      for (int off = 1; off < 16; off <<= 1) {
        s1 += __shfl_xor(s1, off);
        s2 += __shfl_xor(s2, off);
      }
      if (l16 == 0) { red1[row * 4 + w] = s1; red2[row * 4 + w] = s2; }
    }
  __syncthreads();
#pragma unroll
  for (int i = 0; i < 4; i++)
#pragma unroll
    for (int r = 0; r < 4; r++) {
      int row = i * 16 + quad * 4 + r;
      float s1 = red1[row * 4] + red1[row * 4 + 1] + red1[row * 4 + 2] + red1[row * 4 + 3];
      float s2 = red2[row * 4] + red2[row * 4 + 1] + red2[row * 4 + 2] + red2[row * 4 + 3];
      float mean = s1 * (1.f / 256.f);
      float rstd = rsqrtf(s2 * (1.f / 256.f) - mean * mean + 1e-5f);
#pragma unroll
      for (int j = 0; j < 4; j++)
        C[(m0 + row) * 256 + wc + j * 16 + l16] = f2bf((acc[i][j][r] - mean) * rstd);
    }
}

// ---------------- fused FFN: C = LN(h + relu(h W1) W2), 64 rows/block, 4 waves.
// (R0 winner, 158.8 us — restored after R13/R14 showed all alternatives worse)
__global__ __launch_bounds__(256, 2) void ffn_fused(const ushort* __restrict__ H,   // [M x 256]
                                                    const ushort* __restrict__ W1T, // [1024 x 256]
                                                    const ushort* __restrict__ W2T, // [256 x 1024]
                                                    ushort* __restrict__ C,         // [M x 256]
                                                    int M) {
  __shared__ __align__(16) ushort As[8 * 64 * 32];  // h: 8 k-planes x 64 rows (32 KB)
  __shared__ __align__(16) ushort Ss[8 * 64 * 32];  // S macro: 8 planes x 64 rows (32 KB)
  __shared__ __align__(16) ushort Wb[256 * 32];     // weight plane; wave w owns rows w*64.. (16 KB)
  const int tid = threadIdx.x;
  const int w = tid >> 6, lane = tid & 63;
  const int quad = lane >> 4, l16 = lane & 15;
  const long m0 = (long)blockIdx.x * 64;
  const int srow = lane >> 2;
  const int scol = STAGE_COL(lane);

  // stage h tile once: 8 planes x 4 row-groups = 32 insts, 8 per wave
#pragma unroll
  for (int t = 0; t < 8; t++) {
    int p = 2 * w + t / 4, ii = t % 4;
    load_lds16(&H[(m0 + ii * 16 + srow) * 256 + p * 32 + scol], &As[(p * 2048) + (ii * 16) * 32]);
  }
  // prestage FFN1 macro-0 plane-0 weights (wave's own quarter)
#pragma unroll
  for (int ii = 0; ii < 4; ii++)
    load_lds16(&W1T[(long)(w * 64 + ii * 16 + srow) * 256 + scol], &Wb[(w * 64 + ii * 16) * 32]);
  __syncthreads();   // As (cross-wave) + own Wb plane 0 ready

  floatx4 acc2[4][4] = {};
  for (int m = 0; m < 4; m++) {          // ff1 macro of 256
    floatx4 acc1[4][4] = {};
    if (m > 0) {
#pragma unroll
      for (int ii = 0; ii < 4; ii++)
        load_lds16(&W1T[(long)(m * 256 + w * 64 + ii * 16 + srow) * 256 + scol],
                   &Wb[(w * 64 + ii * 16) * 32]);
    }
#pragma unroll 1
    for (int p = 0; p < 8; p++) {        // K(DIM) plane — per-wave fences, no barriers
      WAIT_VM0();                        // own staged plane landed
      shortx8 a[4], b[4];
#pragma unroll
      for (int i = 0; i < 4; i++)
        a[i] = *(const shortx8*)&Wb[FRAG_OFF(w * 64 + i * 16 + l16, quad)];
      WAIT_LGKM0();                      // frags in VGPRs; Wb quarter reusable
      if (p < 7) {
#pragma unroll
        for (int ii = 0; ii < 4; ii++)
          load_lds16(&W1T[(long)(m * 256 + w * 64 + ii * 16 + srow) * 256 + (p + 1) * 32 + scol],
                     &Wb[(w * 64 + ii * 16) * 32]);
      }
#pragma unroll
      for (int j = 0; j < 4; j++)
        b[j] = *(const shortx8*)&As[p * 2048 + FRAG_OFF(j * 16 + l16, quad)];
#pragma unroll
      for (int i = 0; i < 4; i++)
#pragma unroll
        for (int j = 0; j < 4; j++)
          acc1[i][j] = __builtin_amdgcn_mfma_f32_16x16x32_bf16(a[i], b[j], acc1[i][j], 0, 0, 0);
    }
    __syncthreads();   // all waves done reading Ss of macro m-1
    // relu + write S^T into Ss (A-layout, swizzled): 4 consecutive ff1 per store
#pragma unroll
    for (int i = 0; i < 4; i++) {
      int fb = w * 64 + i * 16 + quad * 4;   // ff1-in-macro base, 4 consecutive
      int pf = fb >> 5, c = (fb >> 3) & 3, off = fb & 7;
#pragma unroll
      for (int j = 0; j < 4; j++) {
        int tok = j * 16 + l16;
        ushort4 pk;
        pk.x = f2bf(fmaxf(acc1[i][j][0], 0.f));
        pk.y = f2bf(fmaxf(acc1[i][j][1], 0.f));
        pk.z = f2bf(fmaxf(acc1[i][j][2], 0.f));
        pk.w = f2bf(fmaxf(acc1[i][j][3], 0.f));
        *(ushort4*)&Ss[(pf * 64 + tok) * 32 + ((c ^ ((tok >> 1) & 3)) << 3) + off] = pk;
      }
    }
    __syncthreads();   // Ss visible to all waves
    // ---- FFN2 over this macro: A = S from LDS, B = W2 staged per-wave
#pragma unroll
    for (int jj = 0; jj < 4; jj++)
      load_lds16(&W2T[(long)(w * 64 + jj * 16 + srow) * 1024 + m * 256 + scol],
                 &Wb[(w * 64 + jj * 16) * 32]);
#pragma unroll 1
    for (int p = 0; p < 8; p++) {        // k-plane over ff1 macro — per-wave fences
      WAIT_VM0();
      shortx8 a[4], b[4];
#pragma unroll
      for (int j = 0; j < 4; j++)
        b[j] = *(const shortx8*)&Wb[FRAG_OFF(w * 64 + j * 16 + l16, quad)];
      WAIT_LGKM0();
      if (p < 7) {
#pragma unroll
        for (int jj = 0; jj < 4; jj++)
          load_lds16(&W2T[(long)(w * 64 + jj * 16 + srow) * 1024 + m * 256 + (p + 1) * 32 + scol],
                     &Wb[(w * 64 + jj * 16) * 32]);
      }
#pragma unroll
      for (int i = 0; i < 4; i++)
        a[i] = *(const shortx8*)&Ss[p * 2048 + FRAG_OFF(i * 16 + l16, quad)];
#pragma unroll
      for (int i = 0; i < 4; i++)
#pragma unroll
        for (int j = 0; j < 4; j++)
          acc2[i][j] = __builtin_amdgcn_mfma_f32_16x16x32_bf16(a[i], b[j], acc2[i][j], 0, 0, 0);
    }
  }
  __syncthreads();     // done reading Ss before red arrays alias it

  // epilogue: residual (H) + LN over full 256-col row; red arrays alias dead Ss
  float* red1 = (float*)Ss;
  float* red2 = red1 + 256;
  const int wc = w * 64;
#pragma unroll
  for (int i = 0; i < 4; i++)
#pragma unroll
    for (int r = 0; r < 4; r++) {
      int row = i * 16 + quad * 4 + r;   // 0..63
      float s1 = 0.f, s2 = 0.f;
#pragma unroll
      for (int j = 0; j < 4; j++) {
        float v = acc2[i][j][r] + bf2f(H[(m0 + row) * 256 + wc + j * 16 + l16]);
        acc2[i][j][r] = v;
        s1 += v;
        s2 += v * v;
      }
#pragma unroll
      for (int off = 1; off < 16; off <<= 1) {
        s1 += __shfl_xor(s1, off);
        s2 += __shfl_xor(s2, off);
      }
      if (l16 == 0) { red1[row * 4 + w] = s1; red2[row * 4 + w] = s2; }
    }
  __syncthreads();
#pragma unroll
  for (int i = 0; i < 4; i++)
#pragma unroll
    for (int r = 0; r < 4; r++) {
      int row = i * 16 + quad * 4 + r;
      float s1 = red1[row * 4] + red1[row * 4 + 1] + red1[row * 4 + 2] + red1[row * 4 + 3];
      float s2 = red2[row * 4] + red2[row * 4 + 1] + red2[row * 4 + 2] + red2[row * 4 + 3];
      float mean = s1 * (1.f / 256.f);
      float rstd = rsqrtf(s2 * (1.f / 256.f) - mean * mean + 1e-5f);
      if (m0 + row < M) {
#pragma unroll
        for (int j = 0; j < 4; j++)
          C[(m0 + row) * 256 + wc + j * 16 + l16] = f2bf((acc2[i][j][r] - mean) * rstd);
      }
    }
}

// ---------------- MFMA attention per sequence; o overwrites the q slot of qkv.
// R15: QK^T and PV on matrix cores (old scalar version: MfmaUtil=0, VALU-bound
// at 109 us).  Per wave: 2 heads.  Layouts lifted from the proven gemm_tok64:
// A-frag lane&15 = M-row, quad = k-octet; B-frag lane&15 = N-row; C row =
// quad*4+r, col = l16.  Q/K rows chunk-swizzled ^(row&7); V transposed at load
// into Vt[dim][keyPad32] swizzled ^((dim>>3)&3); P via wave-local LDS
// (swizzle ^((row>>1)&3)).  Pad rows/cols zero-filled; pad keys masked -1e9.
template <int LSEQ, bool MASKED>
__global__ __launch_bounds__(256) void attn(const int* __restrict__ inputs,
                                            ushort* __restrict__ qkv) {
  __shared__ __align__(16) ushort Qs[32 * 256];
  __shared__ __align__(16) ushort Ks[32 * 256];
  __shared__ __align__(16) ushort Vt[256 * 32];    // [dim][keyPad32]
  __shared__ __align__(16) ushort Ps[4 * 32 * 32]; // per-wave P buffer
  __shared__ float pads[32];
  constexpr int MT = (LSEQ + 15) / 16;             // query/key 16-tiles
  const int blk = blockIdx.x;
  const int tid = threadIdx.x;
  const int w = tid >> 6, lane = tid & 63;
  const int quad = lane >> 4, l16 = lane & 15;
  ushort* base = qkv + (size_t)blk * LSEQ * 768;
  const uint4* src = (const uint4*)base;
  const uint4 z4 = {0u, 0u, 0u, 0u};

  // zero Qs/Ks pad rows (LSEQ..31)
  for (int i = tid; i < (32 - LSEQ) * 32 * 2; i += 256) {
    int arr = (i >= (32 - LSEQ) * 32);
    int rem = arr ? i - (32 - LSEQ) * 32 : i;
    int row = LSEQ + (rem >> 5), ch = rem & 31;
    *(uint4*)&((arr ? Ks : Qs)[row * 256 + ch * 8]) = z4;
  }
  // zero Vt pad key-octets (swizzled position per row)
  for (int i = tid; i < 256 * (4 - LSEQ / 8); i += 256) {
    int row = i & 255, pc = LSEQ / 8 + (i >> 8);
    *(uint4*)&Vt[row * 32 + ((pc ^ ((row >> 3) & 3)) * 8)] = z4;
  }
  // zero this wave's Ps (wave-local; covers never-written positions)
  {
    ushort* pz = Ps + w * 1024;
    *(uint4*)&pz[lane * 16] = z4;
    *(uint4*)&pz[lane * 16 + 8] = z4;
  }
  if (tid < 32) {
    float pv = 1.f;
    if (tid < LSEQ) pv = MASKED ? ((inputs[blk * LSEQ + tid] == 0) ? 1.f : 0.f) : 0.f;
    pads[tid] = pv;
  }
  // load q/k (chunk-swizzled) and v (transposed)
  for (int i = tid; i < LSEQ * 96; i += 256) {
    int c = i / 96, part = i % 96;
    uint4 val = src[c * 96 + part];
    int sect = part >> 5, off = part & 31;
    if (sect == 0) {
      *(uint4*)&Qs[c * 256 + ((off ^ (c & 7)) * 8)] = val;
    } else if (sect == 1) {
      *(uint4*)&Ks[c * 256 + ((off ^ (c & 7)) * 8)] = val;
    } else {
      int d0 = (off & 31) * 8;
      const ushort* us = (const ushort*)&val;
#pragma unroll
      for (int j = 0; j < 8; j++) {
        int dim = d0 + j;
        Vt[dim * 32 + (((c >> 3) ^ ((dim >> 3) & 3)) * 8) + (c & 7)] = us[j];
      }
    }
  }
  __syncthreads();

  ushort* Psw = Ps + w * 1024;
#pragma unroll
  for (int t = 0; t < 2; t++) {
    const int h = w * 2 + t, hb = h * 32;
    shortx8 aq[MT], bk[MT];
#pragma unroll
    for (int i = 0; i < MT; i++)
      aq[i] = *(const shortx8*)&Qs[(i * 16 + l16) * 256 + (((h * 4 + quad) ^ (l16 & 7)) * 8)];
#pragma unroll
    for (int j = 0; j < MT; j++)
      bk[j] = *(const shortx8*)&Ks[(j * 16 + l16) * 256 + (((h * 4 + quad) ^ (l16 & 7)) * 8)];
    floatx4 s[MT][MT];
#pragma unroll
    for (int i = 0; i < MT; i++)
#pragma unroll
      for (int j = 0; j < MT; j++) {
        floatx4 zz = {0.f, 0.f, 0.f, 0.f};
        s[i][j] = __builtin_amdgcn_mfma_f32_16x16x32_bf16(aq[i], bk[j], zz, 0, 0, 0);
      }
    float pv[MT];
#pragma unroll
    for (int j = 0; j < MT; j++) pv[j] = pads[j * 16 + l16];
#pragma unroll
    for (int i = 0; i < MT; i++) {
#pragma unroll
      for (int r = 0; r < 4; r++) {
        float v[MT];
        float mx = -3e38f;
#pragma unroll
        for (int j = 0; j < MT; j++) {
          float x = s[i][j][r] * 0.17677669529663687f;
          if (pv[j] != 0.f) x = -1e9f;
          v[j] = x;
          mx = fmaxf(mx, x);
        }
#pragma unroll
        for (int off = 1; off < 16; off <<= 1) mx = fmaxf(mx, __shfl_xor(mx, off));
        float den = 0.f;
#pragma unroll
        for (int j = 0; j < MT; j++) { v[j] = __expf(v[j] - mx); den += v[j]; }
#pragma unroll
        for (int off = 1; off < 16; off <<= 1) den += __shfl_xor(den, off);
        float inv = 1.f / den;
        int row = i * 16 + quad * 4 + r;
#pragma unroll
        for (int j = 0; j < MT; j++) {
          int col = j * 16 + l16;
          Psw[row * 32 + (((col >> 3) ^ ((row >> 1) & 3)) * 8) + (col & 7)] = f2bf(v[j] * inv);
        }
      }
    }
    WAIT_LGKM0();   // wave-local Ps writes complete before A-frag reads
    shortx8 pa[MT], bv[2];
#pragma unroll
    for (int i = 0; i < MT; i++) {
      int row = i * 16 + l16;
      pa[i] = *(const shortx8*)&Psw[row * 32 + ((quad ^ ((row >> 1) & 3)) * 8)];
    }
#pragma unroll
    for (int jj = 0; jj < 2; jj++) {
      int row = hb + jj * 16 + l16;
      bv[jj] = *(const shortx8*)&Vt[row * 32 + ((quad ^ ((row >> 3) & 3)) * 8)];
    }
    floatx4 o[MT][2];
#pragma unroll
    for (int i = 0; i < MT; i++)
#pragma unroll
      for (int jj = 0; jj < 2; jj++) {
        floatx4 zz = {0.f, 0.f, 0.f, 0.f};
        o[i][jj] = __builtin_amdgcn_mfma_f32_16x16x32_bf16(pa[i], bv[jj], zz, 0, 0, 0);
      }
#pragma unroll
    for (int i = 0; i < MT; i++)
#pragma unroll
      for (int r = 0; r < 4; r++) {
        int row = i * 16 + quad * 4 + r;
        if (row < LSEQ) {
#pragma unroll
          for (int jj = 0; jj < 2; jj++)
            base[(size_t)row * 768 + hb + jj * 16 + l16] = f2bf(o[i][jj][r]);
        }
      }
  }
}

// ---------------- masked mean over chars -> scatter into padded + flag real slots
__global__ __launch_bounds__(256) void pool_scatter(const ushort* __restrict__ ft,
                                                    const int* __restrict__ inputs,
                                                    const int* __restrict__ cid,
                                                    const int* __restrict__ wpos,
                                                    ushort* __restrict__ padded,
                                                    int* __restrict__ flags) {
  int w = blockIdx.x, d = threadIdx.x;
  float s = 0.f;
  int cnt = 0;
  for (int c = 0; c < LW; c++) {
    if (inputs[w * LW + c] != 0) {
      s += bf2f(ft[((size_t)w * LW + c) * DIM + d]);
      cnt++;
    }
  }
  int slot = cid[w] * MAXW + wpos[w];
  padded[(size_t)slot * DIM + d] = f2bf(s / (float)cnt);
  if (d == 0) flags[slot] = 1;
}

// ---------------- final: mean over real word rows per concept -> f32 out
__global__ __launch_bounds__(256) void final_pool(const ushort* __restrict__ nft,
                                                  const int* __restrict__ flags,
                                                  float* __restrict__ out) {
  int n = blockIdx.x, d = threadIdx.x;
  float s = 0.f;
  int cnt = 0;
  for (int wd = 0; wd < MAXW; wd++) {
    if (flags[n * MAXW + wd]) {
      s += bf2f(nft[((size_t)n * MAXW + wd) * DIM + d]);
      cnt++;
    }
  }
  out[n * DIM + d] = s / (float)cnt;
}

extern "C" void kernel_launch(void* const* d_in, const int* in_sizes, int n_in,
                              void* d_out, int out_size, void* d_ws, size_t ws_size,
                              hipStream_t stream) {
  const int* inputs = (const int*)d_in[0];
  const int* cid = (const int*)d_in[1];
  const int* wpos = (const int*)d_in[2];
  const float* we_emb = (const float*)d_in[5];
  const float* we_qkv = (const float*)d_in[6];
  const float* we_o = (const float*)d_in[7];
  const float* we_ff1 = (const float*)d_in[8];
  const float* we_ff2 = (const float*)d_in[9];
  const float* ne_qkv = (const float*)d_in[10];
  const float* ne_o = (const float*)d_in[11];
  const float* ne_ff1 = (const float*)d_in[12];
  const float* ne_ff2 = (const float*)d_in[13];
  float* out = (float*)d_out;

  int chunks = 4;
  if (ws_size >= 515000000UL) chunks = 1;
  else if (ws_size >= 263258112UL) chunks = 2;
  const int wpc = NWORDS / chunks;
  const int tpc = wpc * LW;

  const size_t X = (size_t)tpc * DIM * 2;      // x / h size
  const size_t Q = (size_t)tpc * 768 * 2;      // qkv size

  char* base = (char*)d_ws;
  ushort* x = (ushort*)(base);
  ushort* qkv = (ushort*)(base + X);
  ushort* h = (ushort*)(base + X + Q);
  ushort* ft = qkv;                             // qkv dead after o-proj
  size_t pend = X + Q + X;
  ushort* padded = (ushort*)(base + pend);                // 8,388,608 B
  int* flags = (int*)(base + pend + 8388608);             // 65,536 B
  ushort* wT = (ushort*)(base + pend + 8454144);          // 3,145,728 B
  // name-stage buffers alias the word-stage region (dead by then)
  ushort* nqkv = (ushort*)(base);                         // 25,165,824
  ushort* nh = (ushort*)(base + 25165824);                // 8,388,608
  ushort* nft = (ushort*)(base + 33554432);               // 8,388,608

  ushort* wqkvT = wT;
  ushort* woT = wT + 196608;
  ushort* wff1T = wT + 262144;
  ushort* wff2T = wT + 524288;
  ushort* nqkvT = wT + 786432;
  ushort* neoT = wT + 983040;
  ushort* neff1T = wT + 1048576;
  ushort* neff2T = wT + 1310720;

  wprep<<<768, 256, 0, stream>>>(we_qkv, wqkvT, 256, 768);
  wprep<<<256, 256, 0, stream>>>(we_o, woT, 256, 256);
  wprep<<<1024, 256, 0, stream>>>(we_ff1, wff1T, 256, 1024);
  wprep<<<1024, 256, 0, stream>>>(we_ff2, wff2T, 1024, 256);
  wprep<<<768, 256, 0, stream>>>(ne_qkv, nqkvT, 256, 768);
  wprep<<<256, 256, 0, stream>>>(ne_o, neoT, 256, 256);
  wprep<<<1024, 256, 0, stream>>>(ne_ff1, neff1T, 256, 1024);
  wprep<<<1024, 256, 0, stream>>>(ne_ff2, neff2T, 1024, 256);

  (void)hipMemsetAsync(padded, 0, (size_t)TN * DIM * 2, stream);
  (void)hipMemsetAsync(flags, 0, TN * 4, stream);

  for (int c = 0; c < chunks; c++) {
    const int* in_c = inputs + (size_t)c * wpc * LW;
    const int* cid_c = cid + (size_t)c * wpc;
    const int* wpos_c = wpos + (size_t)c * wpc;

    embed4<<<tpc / 4, 256, 0, stream>>>(in_c, we_emb, x, tpc);
    // QKV: 3 N-tiles of 256 over the 768-wide output (blockIdx.x = N-tile)
    {
      dim3 g(3, tpc / 64);
      gemm_tok64<false><<<g, 256, 0, stream>>>(x, 256, wqkvT, nullptr, qkv, 768);
    }
    attn<24, true><<<wpc, 256, 0, stream>>>(in_c, qkv);
    // o-proj + residual(x) + LN -> h   (o lives in the q slot of qkv, lda=768)
    {
      dim3 g(1, tpc / 64);
      gemm_tok64<true><<<g, 256, 0, stream>>>(qkv, 768, woT, x, h, 256);
    }
    ffn_fused<<<tpc / 64, 256, 0, stream>>>(h, wff1T, wff2T, ft, tpc);
    pool_scatter<<<wpc, 256, 0, stream>>>(ft, in_c, cid_c, wpos_c, padded, flags);
  }

  // name-level block
  {
    dim3 g(3, TN / 64);
    gemm_tok64<false><<<g, 256, 0, stream>>>(padded, 256, nqkvT, nullptr, nqkv, 768);
  }
  attn<16, false><<<NCONC, 256, 0, stream>>>(nullptr, nqkv);
  {
    dim3 g(1, TN / 64);
    gemm_tok64<true><<<g, 256, 0, stream>>>(nqkv, 768, neoT, padded, nh, 256);
  }
  ffn_fused<<<TN / 64, 256, 0, stream>>>(nh, neff1T, neff2T, nft, TN);
  final_pool<<<NCONC, 256, 0, stream>>>(nft, flags, out);
}

// Round 16
// 905.077 us; speedup vs baseline: 1.2213x; 1.0345x over previous
//
#include <hip/hip_runtime.h>
#include <hip/hip_bf16.h>

#define NWORDS 8192
#define LW 24
#define DIM 256
#define NHEAD 8
#define DFF 1024
#define NCONC 1024
#define MAXW 16
#define TN (NCONC * MAXW)          // 16384 name tokens

typedef float floatx4 __attribute__((ext_vector_type(4)));
typedef short shortx8 __attribute__((ext_vector_type(8)));

__device__ __forceinline__ float bf2f(ushort u) {
  union { uint u; float f; } v; v.u = ((uint)u) << 16; return v.f;
}
__device__ __forceinline__ ushort f2bf(float f) {
  union { float f; uint u; } v; v.f = f;
  return (ushort)((v.u + 0x7FFFu + ((v.u >> 16) & 1u)) >> 16);
}

// async global->LDS, 16B per lane; LDS dst is wave-uniform base + lane*16
__device__ __forceinline__ void load_lds16(const ushort* gsrc, ushort* lds) {
  __builtin_amdgcn_global_load_lds((const __attribute__((address_space(1))) void*)gsrc,
                                   (__attribute__((address_space(3))) void*)lds, 16, 0, 0);
}

// s_waitcnt imm: vmcnt[3:0]=b3:0,[5:4]=b15:14; expcnt=b6:4; lgkmcnt=b11:8
#define WAIT_VM0() __builtin_amdgcn_s_waitcnt(0x0F70)    // vmcnt(0), others max
#define WAIT_LGKM0() __builtin_amdgcn_s_waitcnt(0xC07F)  // lgkmcnt(0), others max

// Swizzled LDS tile (R6-verified: SQ_LDS_BANK_CONFLICT == 0): rows of 32 ushort
// (64B) in 4 16B chunks; chunk c of row r stored at slot c ^ ((r>>1)&3).
#define STAGE_COL(lane) ((((lane) & 3) ^ (((lane) >> 3) & 3)) * 8)
#define FRAG_OFF(row, quad) (((row) * 32) + ((((quad) ^ (((row) >> 1) & 3))) * 8))

// ---------------- all weight transposes in ONE launch (R16: was 8 launches)
struct WPSeg { const float* W; ushort* WT; int K; int N; int b0; };
struct WPAll { WPSeg seg[8]; };

__global__ __launch_bounds__(256) void wprep_all(WPAll a, int nseg) {
  int b = blockIdx.x;
  int s = 0;
#pragma unroll
  for (int i = 1; i < 8; i++)
    if (i < nseg && b >= a.seg[i].b0) s = i;
  const WPSeg sg = a.seg[s];
  int idx = (b - sg.b0) * 256 + threadIdx.x;
  if (idx < sg.K * sg.N) {
    int k = idx / sg.N, n = idx % sg.N;
    sg.WT[n * sg.K + k] = f2bf(sg.W[idx]);
  }
}

// ---------------- embedding gather -> bf16 x (R16: 1 thread = 8 elems)
__global__ __launch_bounds__(256) void embed8(const int* __restrict__ inputs,
                                              const float* __restrict__ we_emb,
                                              ushort* __restrict__ x, int ntok) {
  int idx = blockIdx.x * 256 + threadIdx.x;
  int t = idx >> 5, d = (idx & 31) * 8;
  if (t < ntok) {
    const float4* src = (const float4*)&we_emb[inputs[t] * DIM + d];
    const float4 f0 = src[0], f1 = src[1];
    uint4 o;
    o.x = (uint)f2bf(f0.x) | ((uint)f2bf(f0.y) << 16);
    o.y = (uint)f2bf(f0.z) | ((uint)f2bf(f0.w) << 16);
    o.z = (uint)f2bf(f1.x) | ((uint)f2bf(f1.y) << 16);
    o.w = (uint)f2bf(f1.z) | ((uint)f2bf(f1.w) << 16);
    *(uint4*)&x[(size_t)t * DIM + d] = o;
  }
}

// ---------------- GEMM, K=256 fixed, 64 tokens/block, N-tile 256 per block
// (R0-proven config: 4 waves / 256 thr; wave owns 64 cols; barrier-free K-loop)
template <bool LN>
__global__ __launch_bounds__(256, 2) void gemm_tok64(const ushort* __restrict__ A, int lda,
                                                     const ushort* __restrict__ BT,  // [N x 256]
                                                     const ushort* __restrict__ RES, // [M x 256] | null
                                                     ushort* __restrict__ C, int ldc) {
  __shared__ __align__(16) ushort As[8 * 64 * 32];  // tokens: 8 k-planes x 64 rows (32 KB)
  __shared__ __align__(16) ushort Wb[256 * 32];     // weight plane; wave w owns rows w*64.. (16 KB)
  __shared__ float red1[64 * 4];
  __shared__ float red2[64 * 4];
  const int tid = threadIdx.x;
  const int w = tid >> 6, lane = tid & 63;
  const int quad = lane >> 4, l16 = lane & 15;
  const long m0 = (long)blockIdx.y * 64;
  const long nb = (long)blockIdx.x * 256;           // N-tile base
  const int srow = lane >> 2;
  const int scol = STAGE_COL(lane);
  const int wc = w * 64;

  // stage A tile once: 8 planes x 4 row-groups = 32 insts, 8 per wave
#pragma unroll
  for (int t = 0; t < 8; t++) {
    int p = 2 * w + t / 4, ii = t % 4;
    load_lds16(&A[(m0 + ii * 16 + srow) * lda + p * 32 + scol], &As[p * 2048 + (ii * 16) * 32]);
  }
  // prestage weight plane 0 (wave's own quarter)
#pragma unroll
  for (int ii = 0; ii < 4; ii++)
    load_lds16(&BT[(nb + wc + ii * 16 + srow) * 256 + scol], &Wb[(wc + ii * 16) * 32]);
  __syncthreads();   // As (cross-wave) + own Wb plane 0 ready

  floatx4 acc[4][4] = {};
#pragma unroll 1
  for (int p = 0; p < 8; p++) {        // K plane — per-wave fences, no barriers
    WAIT_VM0();                        // own staged plane landed
    shortx8 a[4], b[4];
#pragma unroll
    for (int j = 0; j < 4; j++)
      b[j] = *(const shortx8*)&Wb[FRAG_OFF(wc + j * 16 + l16, quad)];
    WAIT_LGKM0();                      // frags in VGPRs; Wb quarter reusable
    if (p < 7) {
#pragma unroll
      for (int ii = 0; ii < 4; ii++)
        load_lds16(&BT[(nb + wc + ii * 16 + srow) * 256 + (p + 1) * 32 + scol],
                   &Wb[(wc + ii * 16) * 32]);
    }
#pragma unroll
    for (int i = 0; i < 4; i++)
      a[i] = *(const shortx8*)&As[p * 2048 + FRAG_OFF(i * 16 + l16, quad)];
#pragma unroll
    for (int i = 0; i < 4; i++)
#pragma unroll
      for (int j = 0; j < 4; j++)
        acc[i][j] = __builtin_amdgcn_mfma_f32_16x16x32_bf16(a[i], b[j], acc[i][j], 0, 0, 0);
  }

  if (!LN) {
    // plain store (used for QKV; C is the 768-wide qkv buffer)
#pragma unroll
    for (int i = 0; i < 4; i++)
#pragma unroll
      for (int j = 0; j < 4; j++)
#pragma unroll
        for (int r = 0; r < 4; r++) {
          long m = m0 + i * 16 + quad * 4 + r;
          C[m * ldc + nb + wc + j * 16 + l16] = f2bf(acc[i][j][r]);
        }
    return;
  }

  // residual + LN epilogue (N==256, gridDim.x==1 -> nb==0)
#pragma unroll
  for (int i = 0; i < 4; i++)
#pragma unroll
    for (int r = 0; r < 4; r++) {
      int row = i * 16 + quad * 4 + r;
      float s1 = 0.f, s2 = 0.f;
#pragma unroll
      for (int j = 0; j < 4; j++) {
        float v = acc[i][j][r] + bf2f(RES[(m0 + row) * 256 + wc + j * 16 + l16]);
        acc[i][j][r] = v;
        s1 += v;
        s2 += v * v;
      }
#pragma unroll
      for (int off = 1; off < 16; off <<= 1) {
        s1 += __shfl_xor(s1, off);
        s2 += __shfl_xor(s2, off);
      }
      if (l16 == 0) { red1[row * 4 + w] = s1; red2[row * 4 + w] = s2; }
    }
  __syncthreads();
#pragma unroll
  for (int i = 0; i < 4; i++)
#pragma unroll
    for (int r = 0; r < 4; r++) {
      int row = i * 16 + quad * 4 + r;
      float s1 = red1[row * 4] + red1[row * 4 + 1] + red1[row * 4 + 2] + red1[row * 4 + 3];
      float s2 = red2[row * 4] + red2[row * 4 + 1] + red2[row * 4 + 2] + red2[row * 4 + 3];
      float mean = s1 * (1.f / 256.f);
      float rstd = rsqrtf(s2 * (1.f / 256.f) - mean * mean + 1e-5f);
#pragma unroll
      for (int j = 0; j < 4; j++)
        C[(m0 + row) * 256 + wc + j * 16 + l16] = f2bf((acc[i][j][r] - mean) * rstd);
    }
}

// ---------------- fused FFN: C = LN(h + relu(h W1) W2), 64 rows/block, 4 waves.
// (R0 winner, ~156 us — structural floor confirmed over R1/R5/R7/R13/R14)
__global__ __launch_bounds__(256, 2) void ffn_fused(const ushort* __restrict__ H,   // [M x 256]
                                                    const ushort* __restrict__ W1T, // [1024 x 256]
                                                    const ushort* __restrict__ W2T, // [256 x 1024]
                                                    ushort* __restrict__ C,         // [M x 256]
                                                    int M) {
  __shared__ __align__(16) ushort As[8 * 64 * 32];  // h: 8 k-planes x 64 rows (32 KB)
  __shared__ __align__(16) ushort Ss[8 * 64 * 32];  // S macro: 8 planes x 64 rows (32 KB)
  __shared__ __align__(16) ushort Wb[256 * 32];     // weight plane; wave w owns rows w*64.. (16 KB)
  const int tid = threadIdx.x;
  const int w = tid >> 6, lane = tid & 63;
  const int quad = lane >> 4, l16 = lane & 15;
  const long m0 = (long)blockIdx.x * 64;
  const int srow = lane >> 2;
  const int scol = STAGE_COL(lane);

  // stage h tile once: 8 planes x 4 row-groups = 32 insts, 8 per wave
#pragma unroll
  for (int t = 0; t < 8; t++) {
    int p = 2 * w + t / 4, ii = t % 4;
    load_lds16(&H[(m0 + ii * 16 + srow) * 256 + p * 32 + scol], &As[(p * 2048) + (ii * 16) * 32]);
  }
  // prestage FFN1 macro-0 plane-0 weights (wave's own quarter)
#pragma unroll
  for (int ii = 0; ii < 4; ii++)
    load_lds16(&W1T[(long)(w * 64 + ii * 16 + srow) * 256 + scol], &Wb[(w * 64 + ii * 16) * 32]);
  __syncthreads();   // As (cross-wave) + own Wb plane 0 ready

  floatx4 acc2[4][4] = {};
  for (int m = 0; m < 4; m++) {          // ff1 macro of 256
    floatx4 acc1[4][4] = {};
    if (m > 0) {
#pragma unroll
      for (int ii = 0; ii < 4; ii++)
        load_lds16(&W1T[(long)(m * 256 + w * 64 + ii * 16 + srow) * 256 + scol],
                   &Wb[(w * 64 + ii * 16) * 32]);
    }
#pragma unroll 1
    for (int p = 0; p < 8; p++) {        // K(DIM) plane — per-wave fences, no barriers
      WAIT_VM0();                        // own staged plane landed
      shortx8 a[4], b[4];
#pragma unroll
      for (int i = 0; i < 4; i++)
        a[i] = *(const shortx8*)&Wb[FRAG_OFF(w * 64 + i * 16 + l16, quad)];
      WAIT_LGKM0();                      // frags in VGPRs; Wb quarter reusable
      if (p < 7) {
#pragma unroll
        for (int ii = 0; ii < 4; ii++)
          load_lds16(&W1T[(long)(m * 256 + w * 64 + ii * 16 + srow) * 256 + (p + 1) * 32 + scol],
                     &Wb[(w * 64 + ii * 16) * 32]);
      }
#pragma unroll
      for (int j = 0; j < 4; j++)
        b[j] = *(const shortx8*)&As[p * 2048 + FRAG_OFF(j * 16 + l16, quad)];
#pragma unroll
      for (int i = 0; i < 4; i++)
#pragma unroll
        for (int j = 0; j < 4; j++)
          acc1[i][j] = __builtin_amdgcn_mfma_f32_16x16x32_bf16(a[i], b[j], acc1[i][j], 0, 0, 0);
    }
    __syncthreads();   // all waves done reading Ss of macro m-1
    // relu + write S^T into Ss (A-layout, swizzled): 4 consecutive ff1 per store
#pragma unroll
    for (int i = 0; i < 4; i++) {
      int fb = w * 64 + i * 16 + quad * 4;   // ff1-in-macro base, 4 consecutive
      int pf = fb >> 5, c = (fb >> 3) & 3, off = fb & 7;
#pragma unroll
      for (int j = 0; j < 4; j++) {
        int tok = j * 16 + l16;
        ushort4 pk;
        pk.x = f2bf(fmaxf(acc1[i][j][0], 0.f));
        pk.y = f2bf(fmaxf(acc1[i][j][1], 0.f));
        pk.z = f2bf(fmaxf(acc1[i][j][2], 0.f));
        pk.w = f2bf(fmaxf(acc1[i][j][3], 0.f));
        *(ushort4*)&Ss[(pf * 64 + tok) * 32 + ((c ^ ((tok >> 1) & 3)) << 3) + off] = pk;
      }
    }
    __syncthreads();   // Ss visible to all waves
    // ---- FFN2 over this macro: A = S from LDS, B = W2 staged per-wave
#pragma unroll
    for (int jj = 0; jj < 4; jj++)
      load_lds16(&W2T[(long)(w * 64 + jj * 16 + srow) * 1024 + m * 256 + scol],
                 &Wb[(w * 64 + jj * 16) * 32]);
#pragma unroll 1
    for (int p = 0; p < 8; p++) {        // k-plane over ff1 macro — per-wave fences
      WAIT_VM0();
      shortx8 a[4], b[4];
#pragma unroll
      for (int j = 0; j < 4; j++)
        b[j] = *(const shortx8*)&Wb[FRAG_OFF(w * 64 + j * 16 + l16, quad)];
      WAIT_LGKM0();
      if (p < 7) {
#pragma unroll
        for (int jj = 0; jj < 4; jj++)
          load_lds16(&W2T[(long)(w * 64 + jj * 16 + srow) * 1024 + m * 256 + (p + 1) * 32 + scol],
                     &Wb[(w * 64 + jj * 16) * 32]);
      }
#pragma unroll
      for (int i = 0; i < 4; i++)
        a[i] = *(const shortx8*)&Ss[p * 2048 + FRAG_OFF(i * 16 + l16, quad)];
#pragma unroll
      for (int i = 0; i < 4; i++)
#pragma unroll
        for (int j = 0; j < 4; j++)
          acc2[i][j] = __builtin_amdgcn_mfma_f32_16x16x32_bf16(a[i], b[j], acc2[i][j], 0, 0, 0);
    }
  }
  __syncthreads();     // done reading Ss before red arrays alias it

  // epilogue: residual (H) + LN over full 256-col row; red arrays alias dead Ss
  float* red1 = (float*)Ss;
  float* red2 = red1 + 256;
  const int wc = w * 64;
#pragma unroll
  for (int i = 0; i < 4; i++)
#pragma unroll
    for (int r = 0; r < 4; r++) {
      int row = i * 16 + quad * 4 + r;   // 0..63
      float s1 = 0.f, s2 = 0.f;
#pragma unroll
      for (int j = 0; j < 4; j++) {
        float v = acc2[i][j][r] + bf2f(H[(m0 + row) * 256 + wc + j * 16 + l16]);
        acc2[i][j][r] = v;
        s1 += v;
        s2 += v * v;
      }
#pragma unroll
      for (int off = 1; off < 16; off <<= 1) {
        s1 += __shfl_xor(s1, off);
        s2 += __shfl_xor(s2, off);
      }
      if (l16 == 0) { red1[row * 4 + w] = s1; red2[row * 4 + w] = s2; }
    }
  __syncthreads();
#pragma unroll
  for (int i = 0; i < 4; i++)
#pragma unroll
    for (int r = 0; r < 4; r++) {
      int row = i * 16 + quad * 4 + r;
      float s1 = red1[row * 4] + red1[row * 4 + 1] + red1[row * 4 + 2] + red1[row * 4 + 3];
      float s2 = red2[row * 4] + red2[row * 4 + 1] + red2[row * 4 + 2] + red2[row * 4 + 3];
      float mean = s1 * (1.f / 256.f);
      float rstd = rsqrtf(s2 * (1.f / 256.f) - mean * mean + 1e-5f);
      if (m0 + row < M) {
#pragma unroll
        for (int j = 0; j < 4; j++)
          C[(m0 + row) * 256 + wc + j * 16 + l16] = f2bf((acc2[i][j][r] - mean) * rstd);
      }
    }
}

// ---------------- MFMA attention per sequence; o overwrites the q slot of qkv.
// (R15 winner: 109 us scalar -> off the top-5; layouts verified vs reference)
template <int LSEQ, bool MASKED>
__global__ __launch_bounds__(256) void attn(const int* __restrict__ inputs,
                                            ushort* __restrict__ qkv) {
  __shared__ __align__(16) ushort Qs[32 * 256];
  __shared__ __align__(16) ushort Ks[32 * 256];
  __shared__ __align__(16) ushort Vt[256 * 32];    // [dim][keyPad32]
  __shared__ __align__(16) ushort Ps[4 * 32 * 32]; // per-wave P buffer
  __shared__ float pads[32];
  constexpr int MT = (LSEQ + 15) / 16;             // query/key 16-tiles
  const int blk = blockIdx.x;
  const int tid = threadIdx.x;
  const int w = tid >> 6, lane = tid & 63;
  const int quad = lane >> 4, l16 = lane & 15;
  ushort* base = qkv + (size_t)blk * LSEQ * 768;
  const uint4* src = (const uint4*)base;
  const uint4 z4 = {0u, 0u, 0u, 0u};

  // zero Qs/Ks pad rows (LSEQ..31)
  for (int i = tid; i < (32 - LSEQ) * 32 * 2; i += 256) {
    int arr = (i >= (32 - LSEQ) * 32);
    int rem = arr ? i - (32 - LSEQ) * 32 : i;
    int row = LSEQ + (rem >> 5), ch = rem & 31;
    *(uint4*)&((arr ? Ks : Qs)[row * 256 + ch * 8]) = z4;
  }
  // zero Vt pad key-octets (swizzled position per row)
  for (int i = tid; i < 256 * (4 - LSEQ / 8); i += 256) {
    int row = i & 255, pc = LSEQ / 8 + (i >> 8);
    *(uint4*)&Vt[row * 32 + ((pc ^ ((row >> 3) & 3)) * 8)] = z4;
  }
  // zero this wave's Ps (wave-local; covers never-written positions)
  {
    ushort* pz = Ps + w * 1024;
    *(uint4*)&pz[lane * 16] = z4;
    *(uint4*)&pz[lane * 16 + 8] = z4;
  }
  if (tid < 32) {
    float pv = 1.f;
    if (tid < LSEQ) pv = MASKED ? ((inputs[blk * LSEQ + tid] == 0) ? 1.f : 0.f) : 0.f;
    pads[tid] = pv;
  }
  // load q/k (chunk-swizzled) and v (transposed)
  for (int i = tid; i < LSEQ * 96; i += 256) {
    int c = i / 96, part = i % 96;
    uint4 val = src[c * 96 + part];
    int sect = part >> 5, off = part & 31;
    if (sect == 0) {
      *(uint4*)&Qs[c * 256 + ((off ^ (c & 7)) * 8)] = val;
    } else if (sect == 1) {
      *(uint4*)&Ks[c * 256 + ((off ^ (c & 7)) * 8)] = val;
    } else {
      int d0 = (off & 31) * 8;
      const ushort* us = (const ushort*)&val;
#pragma unroll
      for (int j = 0; j < 8; j++) {
        int dim = d0 + j;
        Vt[dim * 32 + (((c >> 3) ^ ((dim >> 3) & 3)) * 8) + (c & 7)] = us[j];
      }
    }
  }
  __syncthreads();

  ushort* Psw = Ps + w * 1024;
#pragma unroll
  for (int t = 0; t < 2; t++) {
    const int h = w * 2 + t, hb = h * 32;
    shortx8 aq[MT], bk[MT];
#pragma unroll
    for (int i = 0; i < MT; i++)
      aq[i] = *(const shortx8*)&Qs[(i * 16 + l16) * 256 + (((h * 4 + quad) ^ (l16 & 7)) * 8)];
#pragma unroll
    for (int j = 0; j < MT; j++)
      bk[j] = *(const shortx8*)&Ks[(j * 16 + l16) * 256 + (((h * 4 + quad) ^ (l16 & 7)) * 8)];
    floatx4 s[MT][MT];
#pragma unroll
    for (int i = 0; i < MT; i++)
#pragma unroll
      for (int j = 0; j < MT; j++) {
        floatx4 zz = {0.f, 0.f, 0.f, 0.f};
        s[i][j] = __builtin_amdgcn_mfma_f32_16x16x32_bf16(aq[i], bk[j], zz, 0, 0, 0);
      }
    float pv[MT];
#pragma unroll
    for (int j = 0; j < MT; j++) pv[j] = pads[j * 16 + l16];
#pragma unroll
    for (int i = 0; i < MT; i++) {
#pragma unroll
      for (int r = 0; r < 4; r++) {
        float v[MT];
        float mx = -3e38f;
#pragma unroll
        for (int j = 0; j < MT; j++) {
          float x = s[i][j][r] * 0.17677669529663687f;
          if (pv[j] != 0.f) x = -1e9f;
          v[j] = x;
          mx = fmaxf(mx, x);
        }
#pragma unroll
        for (int off = 1; off < 16; off <<= 1) mx = fmaxf(mx, __shfl_xor(mx, off));
        float den = 0.f;
#pragma unroll
        for (int j = 0; j < MT; j++) { v[j] = __expf(v[j] - mx); den += v[j]; }
#pragma unroll
        for (int off = 1; off < 16; off <<= 1) den += __shfl_xor(den, off);
        float inv = 1.f / den;
        int row = i * 16 + quad * 4 + r;
#pragma unroll
        for (int j = 0; j < MT; j++) {
          int col = j * 16 + l16;
          Psw[row * 32 + (((col >> 3) ^ ((row >> 1) & 3)) * 8) + (col & 7)] = f2bf(v[j] * inv);
        }
      }
    }
    WAIT_LGKM0();   // wave-local Ps writes complete before A-frag reads
    shortx8 pa[MT], bv[2];
#pragma unroll
    for (int i = 0; i < MT; i++) {
      int row = i * 16 + l16;
      pa[i] = *(const shortx8*)&Psw[row * 32 + ((quad ^ ((row >> 1) & 3)) * 8)];
    }
#pragma unroll
    for (int jj = 0; jj < 2; jj++) {
      int row = hb + jj * 16 + l16;
      bv[jj] = *(const shortx8*)&Vt[row * 32 + ((quad ^ ((row >> 3) & 3)) * 8)];
    }
    floatx4 o[MT][2];
#pragma unroll
    for (int i = 0; i < MT; i++)
#pragma unroll
      for (int jj = 0; jj < 2; jj++) {
        floatx4 zz = {0.f, 0.f, 0.f, 0.f};
        o[i][jj] = __builtin_amdgcn_mfma_f32_16x16x32_bf16(pa[i], bv[jj], zz, 0, 0, 0);
      }
#pragma unroll
    for (int i = 0; i < MT; i++)
#pragma unroll
      for (int r = 0; r < 4; r++) {
        int row = i * 16 + quad * 4 + r;
        if (row < LSEQ) {
#pragma unroll
          for (int jj = 0; jj < 2; jj++)
            base[(size_t)row * 768 + hb + jj * 16 + l16] = f2bf(o[i][jj][r]);
        }
      }
  }
}

// ---------------- masked mean over chars -> scatter into padded + flag real slots
__global__ __launch_bounds__(256) void pool_scatter(const ushort* __restrict__ ft,
                                                    const int* __restrict__ inputs,
                                                    const int* __restrict__ cid,
                                                    const int* __restrict__ wpos,
                                                    ushort* __restrict__ padded,
                                                    int* __restrict__ flags) {
  int w = blockIdx.x, d = threadIdx.x;
  float s = 0.f;
  int cnt = 0;
  for (int c = 0; c < LW; c++) {
    if (inputs[w * LW + c] != 0) {
      s += bf2f(ft[((size_t)w * LW + c) * DIM + d]);
      cnt++;
    }
  }
  int slot = cid[w] * MAXW + wpos[w];
  padded[(size_t)slot * DIM + d] = f2bf(s / (float)cnt);
  if (d == 0) flags[slot] = 1;
}

// ---------------- final: mean over real word rows per concept -> f32 out
__global__ __launch_bounds__(256) void final_pool(const ushort* __restrict__ nft,
                                                  const int* __restrict__ flags,
                                                  float* __restrict__ out) {
  int n = blockIdx.x, d = threadIdx.x;
  float s = 0.f;
  int cnt = 0;
  for (int wd = 0; wd < MAXW; wd++) {
    if (flags[n * MAXW + wd]) {
      s += bf2f(nft[((size_t)n * MAXW + wd) * DIM + d]);
      cnt++;
    }
  }
  out[n * DIM + d] = s / (float)cnt;
}

extern "C" void kernel_launch(void* const* d_in, const int* in_sizes, int n_in,
                              void* d_out, int out_size, void* d_ws, size_t ws_size,
                              hipStream_t stream) {
  const int* inputs = (const int*)d_in[0];
  const int* cid = (const int*)d_in[1];
  const int* wpos = (const int*)d_in[2];
  const float* we_emb = (const float*)d_in[5];
  const float* we_qkv = (const float*)d_in[6];
  const float* we_o = (const float*)d_in[7];
  const float* we_ff1 = (const float*)d_in[8];
  const float* we_ff2 = (const float*)d_in[9];
  const float* ne_qkv = (const float*)d_in[10];
  const float* ne_o = (const float*)d_in[11];
  const float* ne_ff1 = (const float*)d_in[12];
  const float* ne_ff2 = (const float*)d_in[13];
  float* out = (float*)d_out;

  int chunks = 4;
  if (ws_size >= 515000000UL) chunks = 1;
  else if (ws_size >= 263258112UL) chunks = 2;
  const int wpc = NWORDS / chunks;
  const int tpc = wpc * LW;

  const size_t X = (size_t)tpc * DIM * 2;      // x / h size
  const size_t Q = (size_t)tpc * 768 * 2;      // qkv size

  char* base = (char*)d_ws;
  ushort* x = (ushort*)(base);
  ushort* qkv = (ushort*)(base + X);
  ushort* h = (ushort*)(base + X + Q);
  ushort* ft = qkv;                             // qkv dead after o-proj
  size_t pend = X + Q + X;
  ushort* padded = (ushort*)(base + pend);                // 8,388,608 B
  int* flags = (int*)(base + pend + 8388608);             // 65,536 B
  ushort* wT = (ushort*)(base + pend + 8454144);          // 3,145,728 B
  // name-stage buffers alias the word-stage region (dead by then)
  ushort* nqkv = (ushort*)(base);                         // 25,165,824
  ushort* nh = (ushort*)(base + 25165824);                // 8,388,608
  ushort* nft = (ushort*)(base + 33554432);               // 8,388,608

  ushort* wqkvT = wT;
  ushort* woT = wT + 196608;
  ushort* wff1T = wT + 262144;
  ushort* wff2T = wT + 524288;
  ushort* nqkvT = wT + 786432;
  ushort* neoT = wT + 983040;
  ushort* neff1T = wT + 1048576;
  ushort* neff2T = wT + 1310720;

  // single launch for all 8 weight transposes (was 8 launches)
  {
    WPAll a;
    a.seg[0] = {we_qkv, wqkvT, 256, 768, 0};
    a.seg[1] = {we_o, woT, 256, 256, 768};
    a.seg[2] = {we_ff1, wff1T, 256, 1024, 1024};
    a.seg[3] = {we_ff2, wff2T, 1024, 256, 2048};
    a.seg[4] = {ne_qkv, nqkvT, 256, 768, 3072};
    a.seg[5] = {ne_o, neoT, 256, 256, 3840};
    a.seg[6] = {ne_ff1, neff1T, 256, 1024, 4096};
    a.seg[7] = {ne_ff2, neff2T, 1024, 256, 5120};
    wprep_all<<<6144, 256, 0, stream>>>(a, 8);
  }

  (void)hipMemsetAsync(padded, 0, (size_t)TN * DIM * 2, stream);
  (void)hipMemsetAsync(flags, 0, TN * 4, stream);

  for (int c = 0; c < chunks; c++) {
    const int* in_c = inputs + (size_t)c * wpc * LW;
    const int* cid_c = cid + (size_t)c * wpc;
    const int* wpos_c = wpos + (size_t)c * wpc;

    embed8<<<tpc / 8, 256, 0, stream>>>(in_c, we_emb, x, tpc);
    // QKV: 3 N-tiles of 256 over the 768-wide output (blockIdx.x = N-tile)
    {
      dim3 g(3, tpc / 64);
      gemm_tok64<false><<<g, 256, 0, stream>>>(x, 256, wqkvT, nullptr, qkv, 768);
    }
    attn<24, true><<<wpc, 256, 0, stream>>>(in_c, qkv);
    // o-proj + residual(x) + LN -> h   (o lives in the q slot of qkv, lda=768)
    {
      dim3 g(1, tpc / 64);
      gemm_tok64<true><<<g, 256, 0, stream>>>(qkv, 768, woT, x, h, 256);
    }
    ffn_fused<<<tpc / 64, 256, 0, stream>>>(h, wff1T, wff2T, ft, tpc);
    pool_scatter<<<wpc, 256, 0, stream>>>(ft, in_c, cid_c, wpos_c, padded, flags);
  }

  // name-level block
  {
    dim3 g(3, TN / 64);
    gemm_tok64<false><<<g, 256, 0, stream>>>(padded, 256, nqkvT, nullptr, nqkv, 768);
  }
  attn<16, false><<<NCONC, 256, 0, stream>>>(nullptr, nqkv);
  {
    dim3 g(1, TN / 64);
    gemm_tok64<true><<<g, 256, 0, stream>>>(nqkv, 768, neoT, padded, nh, 256);
  }
  ffn_fused<<<TN / 64, 256, 0, stream>>>(nh, neff1T, neff2T, nft, TN);
  final_pool<<<NCONC, 256, 0, stream>>>(nft, flags, out);
}

// Round 17
// 883.770 us; speedup vs baseline: 1.2508x; 1.0241x over previous
//
#include <hip/hip_runtime.h>
#include <hip/hip_bf16.h>

#define NWORDS 8192
#define LW 24
#define DIM 256
#define NHEAD 8
#define DFF 1024
#define NCONC 1024
#define MAXW 16
#define TN (NCONC * MAXW)          // 16384 name tokens

typedef float floatx4 __attribute__((ext_vector_type(4)));
typedef short shortx8 __attribute__((ext_vector_type(8)));

__device__ __forceinline__ float bf2f(ushort u) {
  union { uint u; float f; } v; v.u = ((uint)u) << 16; return v.f;
}
// R17: compiler-recognized bf16 cast (RNE, same as old bit-twiddle) so adjacent
// converts fuse into v_cvt_pk_bf16_f32 (old hand-rolled form = 4 VALU each).
__device__ __forceinline__ ushort f2bf(float f) {
  __hip_bfloat16 h = __float2bfloat16(f);
  return *reinterpret_cast<ushort*>(&h);
}

// async global->LDS, 16B per lane; LDS dst is wave-uniform base + lane*16
__device__ __forceinline__ void load_lds16(const ushort* gsrc, ushort* lds) {
  __builtin_amdgcn_global_load_lds((const __attribute__((address_space(1))) void*)gsrc,
                                   (__attribute__((address_space(3))) void*)lds, 16, 0, 0);
}

// s_waitcnt imm: vmcnt[3:0]=b3:0,[5:4]=b15:14; expcnt=b6:4; lgkmcnt=b11:8
#define WAIT_VM0() __builtin_amdgcn_s_waitcnt(0x0F70)    // vmcnt(0), others max
#define WAIT_LGKM0() __builtin_amdgcn_s_waitcnt(0xC07F)  // lgkmcnt(0), others max

// Swizzled LDS tile (R6-verified: SQ_LDS_BANK_CONFLICT == 0): rows of 32 ushort
// (64B) in 4 16B chunks; chunk c of row r stored at slot c ^ ((r>>1)&3).
#define STAGE_COL(lane) ((((lane) & 3) ^ (((lane) >> 3) & 3)) * 8)
#define FRAG_OFF(row, quad) (((row) * 32) + ((((quad) ^ (((row) >> 1) & 3))) * 8))

// ---------------- all weight transposes in ONE launch
struct WPSeg { const float* W; ushort* WT; int K; int N; int b0; };
struct WPAll { WPSeg seg[8]; };

__global__ __launch_bounds__(256) void wprep_all(WPAll a, int nseg) {
  int b = blockIdx.x;
  int s = 0;
#pragma unroll
  for (int i = 1; i < 8; i++)
    if (i < nseg && b >= a.seg[i].b0) s = i;
  const WPSeg sg = a.seg[s];
  int idx = (b - sg.b0) * 256 + threadIdx.x;
  if (idx < sg.K * sg.N) {
    int k = idx / sg.N, n = idx % sg.N;
    sg.WT[n * sg.K + k] = f2bf(sg.W[idx]);
  }
}

// ---------------- embedding gather -> bf16 x (1 thread = 8 elems)
__global__ __launch_bounds__(256) void embed8(const int* __restrict__ inputs,
                                              const float* __restrict__ we_emb,
                                              ushort* __restrict__ x, int ntok) {
  int idx = blockIdx.x * 256 + threadIdx.x;
  int t = idx >> 5, d = (idx & 31) * 8;
  if (t < ntok) {
    const float4* src = (const float4*)&we_emb[inputs[t] * DIM + d];
    const float4 f0 = src[0], f1 = src[1];
    uint4 o;
    o.x = (uint)f2bf(f0.x) | ((uint)f2bf(f0.y) << 16);
    o.y = (uint)f2bf(f0.z) | ((uint)f2bf(f0.w) << 16);
    o.z = (uint)f2bf(f1.x) | ((uint)f2bf(f1.y) << 16);
    o.w = (uint)f2bf(f1.z) | ((uint)f2bf(f1.w) << 16);
    *(uint4*)&x[(size_t)t * DIM + d] = o;
  }
}

// ---------------- GEMM, K=256 fixed, 64 tokens/block, NTILES N-tiles of 256.
// R17: NTILES>1 (QKV) stages the A-tile ONCE and loops the proven barrier-free
// plane loop over N-tiles (was grid (3,M/64): A staged 3x redundantly).  At
// p==7 of tile nt the next tile's plane-0 weights are prefetched, preserving
// the per-wave fence discipline.  NTILES==1 is codegen-identical to R16.
template <bool LN, int NTILES>
__global__ __launch_bounds__(256, 2) void gemm_tok64(const ushort* __restrict__ A, int lda,
                                                     const ushort* __restrict__ BT,  // [N x 256]
                                                     const ushort* __restrict__ RES, // [M x 256] | null
                                                     ushort* __restrict__ C, int ldc) {
  __shared__ __align__(16) ushort As[8 * 64 * 32];  // tokens: 8 k-planes x 64 rows (32 KB)
  __shared__ __align__(16) ushort Wb[256 * 32];     // weight plane; wave w owns rows w*64.. (16 KB)
  __shared__ float red1[64 * 4];
  __shared__ float red2[64 * 4];
  const int tid = threadIdx.x;
  const int w = tid >> 6, lane = tid & 63;
  const int quad = lane >> 4, l16 = lane & 15;
  const long m0 = (long)blockIdx.y * 64;
  const long nb0 = (long)blockIdx.x * NTILES * 256; // first N-tile base
  const int srow = lane >> 2;
  const int scol = STAGE_COL(lane);
  const int wc = w * 64;

  // stage A tile once: 8 planes x 4 row-groups = 32 insts, 8 per wave
#pragma unroll
  for (int t = 0; t < 8; t++) {
    int p = 2 * w + t / 4, ii = t % 4;
    load_lds16(&A[(m0 + ii * 16 + srow) * lda + p * 32 + scol], &As[p * 2048 + (ii * 16) * 32]);
  }
  // prestage weight plane 0 of tile 0 (wave's own quarter)
#pragma unroll
  for (int ii = 0; ii < 4; ii++)
    load_lds16(&BT[(nb0 + wc + ii * 16 + srow) * 256 + scol], &Wb[(wc + ii * 16) * 32]);
  __syncthreads();   // As (cross-wave) + own Wb plane 0 ready

#pragma unroll 1
  for (int nt = 0; nt < NTILES; nt++) {
    const long nb = nb0 + (long)nt * 256;
    floatx4 acc[4][4] = {};
#pragma unroll 1
    for (int p = 0; p < 8; p++) {      // K plane — per-wave fences, no barriers
      WAIT_VM0();                      // own staged plane landed (+ prior tile's stores)
      shortx8 a[4], b[4];
#pragma unroll
      for (int j = 0; j < 4; j++)
        b[j] = *(const shortx8*)&Wb[FRAG_OFF(wc + j * 16 + l16, quad)];
      WAIT_LGKM0();                    // frags in VGPRs; Wb quarter reusable
      if (p < 7) {
#pragma unroll
        for (int ii = 0; ii < 4; ii++)
          load_lds16(&BT[(nb + wc + ii * 16 + srow) * 256 + (p + 1) * 32 + scol],
                     &Wb[(wc + ii * 16) * 32]);
      } else if (nt < NTILES - 1) {    // prefetch next tile's plane 0
#pragma unroll
        for (int ii = 0; ii < 4; ii++)
          load_lds16(&BT[(nb + 256 + wc + ii * 16 + srow) * 256 + scol],
                     &Wb[(wc + ii * 16) * 32]);
      }
#pragma unroll
      for (int i = 0; i < 4; i++)
        a[i] = *(const shortx8*)&As[p * 2048 + FRAG_OFF(i * 16 + l16, quad)];
#pragma unroll
      for (int i = 0; i < 4; i++)
#pragma unroll
        for (int j = 0; j < 4; j++)
          acc[i][j] = __builtin_amdgcn_mfma_f32_16x16x32_bf16(a[i], b[j], acc[i][j], 0, 0, 0);
    }

    if (!LN) {
      // plain store (QKV; C is the 768-wide qkv buffer)
#pragma unroll
      for (int i = 0; i < 4; i++)
#pragma unroll
        for (int j = 0; j < 4; j++)
#pragma unroll
          for (int r = 0; r < 4; r++) {
            long m = m0 + i * 16 + quad * 4 + r;
            C[m * ldc + nb + wc + j * 16 + l16] = f2bf(acc[i][j][r]);
          }
    } else {
      // residual + LN epilogue (NTILES==1, N==256, gridDim.x==1 -> nb==0)
#pragma unroll
      for (int i = 0; i < 4; i++)
#pragma unroll
        for (int r = 0; r < 4; r++) {
          int row = i * 16 + quad * 4 + r;
          float s1 = 0.f, s2 = 0.f;
#pragma unroll
          for (int j = 0; j < 4; j++) {
            float v = acc[i][j][r] + bf2f(RES[(m0 + row) * 256 + wc + j * 16 + l16]);
            acc[i][j][r] = v;
            s1 += v;
            s2 += v * v;
          }
#pragma unroll
          for (int off = 1; off < 16; off <<= 1) {
            s1 += __shfl_xor(s1, off);
            s2 += __shfl_xor(s2, off);
          }
          if (l16 == 0) { red1[row * 4 + w] = s1; red2[row * 4 + w] = s2; }
        }
      __syncthreads();
#pragma unroll
      for (int i = 0; i < 4; i++)
#pragma unroll
        for (int r = 0; r < 4; r++) {
          int row = i * 16 + quad * 4 + r;
          float s1 = red1[row * 4] + red1[row * 4 + 1] + red1[row * 4 + 2] + red1[row * 4 + 3];
          float s2 = red2[row * 4] + red2[row * 4 + 1] + red2[row * 4 + 2] + red2[row * 4 + 3];
          float mean = s1 * (1.f / 256.f);
          float rstd = rsqrtf(s2 * (1.f / 256.f) - mean * mean + 1e-5f);
#pragma unroll
          for (int j = 0; j < 4; j++)
            C[(m0 + row) * 256 + wc + j * 16 + l16] = f2bf((acc[i][j][r] - mean) * rstd);
        }
    }
  }
}

// ---------------- fused FFN: C = LN(h + relu(h W1) W2), 64 rows/block, 4 waves.
// (R0 winner, ~157 us — structural floor confirmed over R1/R5/R7/R13/R14)
__global__ __launch_bounds__(256, 2) void ffn_fused(const ushort* __restrict__ H,   // [M x 256]
                                                    const ushort* __restrict__ W1T, // [1024 x 256]
                                                    const ushort* __restrict__ W2T, // [256 x 1024]
                                                    ushort* __restrict__ C,         // [M x 256]
                                                    int M) {
  __shared__ __align__(16) ushort As[8 * 64 * 32];  // h: 8 k-planes x 64 rows (32 KB)
  __shared__ __align__(16) ushort Ss[8 * 64 * 32];  // S macro: 8 planes x 64 rows (32 KB)
  __shared__ __align__(16) ushort Wb[256 * 32];     // weight plane; wave w owns rows w*64.. (16 KB)
  const int tid = threadIdx.x;
  const int w = tid >> 6, lane = tid & 63;
  const int quad = lane >> 4, l16 = lane & 15;
  const long m0 = (long)blockIdx.x * 64;
  const int srow = lane >> 2;
  const int scol = STAGE_COL(lane);

  // stage h tile once: 8 planes x 4 row-groups = 32 insts, 8 per wave
#pragma unroll
  for (int t = 0; t < 8; t++) {
    int p = 2 * w + t / 4, ii = t % 4;
    load_lds16(&H[(m0 + ii * 16 + srow) * 256 + p * 32 + scol], &As[(p * 2048) + (ii * 16) * 32]);
  }
  // prestage FFN1 macro-0 plane-0 weights (wave's own quarter)
#pragma unroll
  for (int ii = 0; ii < 4; ii++)
    load_lds16(&W1T[(long)(w * 64 + ii * 16 + srow) * 256 + scol], &Wb[(w * 64 + ii * 16) * 32]);
  __syncthreads();   // As (cross-wave) + own Wb plane 0 ready

  floatx4 acc2[4][4] = {};
  for (int m = 0; m < 4; m++) {          // ff1 macro of 256
    floatx4 acc1[4][4] = {};
    if (m > 0) {
#pragma unroll
      for (int ii = 0; ii < 4; ii++)
        load_lds16(&W1T[(long)(m * 256 + w * 64 + ii * 16 + srow) * 256 + scol],
                   &Wb[(w * 64 + ii * 16) * 32]);
    }
#pragma unroll 1
    for (int p = 0; p < 8; p++) {        // K(DIM) plane — per-wave fences, no barriers
      WAIT_VM0();                        // own staged plane landed
      shortx8 a[4], b[4];
#pragma unroll
      for (int i = 0; i < 4; i++)
        a[i] = *(const shortx8*)&Wb[FRAG_OFF(w * 64 + i * 16 + l16, quad)];
      WAIT_LGKM0();                      // frags in VGPRs; Wb quarter reusable
      if (p < 7) {
#pragma unroll
        for (int ii = 0; ii < 4; ii++)
          load_lds16(&W1T[(long)(m * 256 + w * 64 + ii * 16 + srow) * 256 + (p + 1) * 32 + scol],
                     &Wb[(w * 64 + ii * 16) * 32]);
      }
#pragma unroll
      for (int j = 0; j < 4; j++)
        b[j] = *(const shortx8*)&As[p * 2048 + FRAG_OFF(j * 16 + l16, quad)];
#pragma unroll
      for (int i = 0; i < 4; i++)
#pragma unroll
        for (int j = 0; j < 4; j++)
          acc1[i][j] = __builtin_amdgcn_mfma_f32_16x16x32_bf16(a[i], b[j], acc1[i][j], 0, 0, 0);
    }
    __syncthreads();   // all waves done reading Ss of macro m-1
    // relu + write S^T into Ss (A-layout, swizzled): 4 consecutive ff1 per store
#pragma unroll
    for (int i = 0; i < 4; i++) {
      int fb = w * 64 + i * 16 + quad * 4;   // ff1-in-macro base, 4 consecutive
      int pf = fb >> 5, c = (fb >> 3) & 3, off = fb & 7;
#pragma unroll
      for (int j = 0; j < 4; j++) {
        int tok = j * 16 + l16;
        ushort4 pk;
        pk.x = f2bf(fmaxf(acc1[i][j][0], 0.f));
        pk.y = f2bf(fmaxf(acc1[i][j][1], 0.f));
        pk.z = f2bf(fmaxf(acc1[i][j][2], 0.f));
        pk.w = f2bf(fmaxf(acc1[i][j][3], 0.f));
        *(ushort4*)&Ss[(pf * 64 + tok) * 32 + ((c ^ ((tok >> 1) & 3)) << 3) + off] = pk;
      }
    }
    __syncthreads();   // Ss visible to all waves
    // ---- FFN2 over this macro: A = S from LDS, B = W2 staged per-wave
#pragma unroll
    for (int jj = 0; jj < 4; jj++)
      load_lds16(&W2T[(long)(w * 64 + jj * 16 + srow) * 1024 + m * 256 + scol],
                 &Wb[(w * 64 + jj * 16) * 32]);
#pragma unroll 1
    for (int p = 0; p < 8; p++) {        // k-plane over ff1 macro — per-wave fences
      WAIT_VM0();
      shortx8 a[4], b[4];
#pragma unroll
      for (int j = 0; j < 4; j++)
        b[j] = *(const shortx8*)&Wb[FRAG_OFF(w * 64 + j * 16 + l16, quad)];
      WAIT_LGKM0();
      if (p < 7) {
#pragma unroll
        for (int jj = 0; jj < 4; jj++)
          load_lds16(&W2T[(long)(w * 64 + jj * 16 + srow) * 1024 + m * 256 + (p + 1) * 32 + scol],
                     &Wb[(w * 64 + jj * 16) * 32]);
      }
#pragma unroll
      for (int i = 0; i < 4; i++)
        a[i] = *(const shortx8*)&Ss[p * 2048 + FRAG_OFF(i * 16 + l16, quad)];
#pragma unroll
      for (int i = 0; i < 4; i++)
#pragma unroll
        for (int j = 0; j < 4; j++)
          acc2[i][j] = __builtin_amdgcn_mfma_f32_16x16x32_bf16(a[i], b[j], acc2[i][j], 0, 0, 0);
    }
  }
  __syncthreads();     // done reading Ss before red arrays alias it

  // epilogue: residual (H) + LN over full 256-col row; red arrays alias dead Ss
  float* red1 = (float*)Ss;
  float* red2 = red1 + 256;
  const int wc = w * 64;
#pragma unroll
  for (int i = 0; i < 4; i++)
#pragma unroll
    for (int r = 0; r < 4; r++) {
      int row = i * 16 + quad * 4 + r;   // 0..63
      float s1 = 0.f, s2 = 0.f;
#pragma unroll
      for (int j = 0; j < 4; j++) {
        float v = acc2[i][j][r] + bf2f(H[(m0 + row) * 256 + wc + j * 16 + l16]);
        acc2[i][j][r] = v;
        s1 += v;
        s2 += v * v;
      }
#pragma unroll
      for (int off = 1; off < 16; off <<= 1) {
        s1 += __shfl_xor(s1, off);
        s2 += __shfl_xor(s2, off);
      }
      if (l16 == 0) { red1[row * 4 + w] = s1; red2[row * 4 + w] = s2; }
    }
  __syncthreads();
#pragma unroll
  for (int i = 0; i < 4; i++)
#pragma unroll
    for (int r = 0; r < 4; r++) {
      int row = i * 16 + quad * 4 + r;
      float s1 = red1[row * 4] + red1[row * 4 + 1] + red1[row * 4 + 2] + red1[row * 4 + 3];
      float s2 = red2[row * 4] + red2[row * 4 + 1] + red2[row * 4 + 2] + red2[row * 4 + 3];
      float mean = s1 * (1.f / 256.f);
      float rstd = rsqrtf(s2 * (1.f / 256.f) - mean * mean + 1e-5f);
      if (m0 + row < M) {
#pragma unroll
        for (int j = 0; j < 4; j++)
          C[(m0 + row) * 256 + wc + j * 16 + l16] = f2bf((acc2[i][j][r] - mean) * rstd);
      }
    }
}

// ---------------- MFMA attention per sequence; o overwrites the q slot of qkv.
// (R15 winner: 109 us scalar -> off the top-5; layouts verified vs reference)
template <int LSEQ, bool MASKED>
__global__ __launch_bounds__(256) void attn(const int* __restrict__ inputs,
                                            ushort* __restrict__ qkv) {
  __shared__ __align__(16) ushort Qs[32 * 256];
  __shared__ __align__(16) ushort Ks[32 * 256];
  __shared__ __align__(16) ushort Vt[256 * 32];    // [dim][keyPad32]
  __shared__ __align__(16) ushort Ps[4 * 32 * 32]; // per-wave P buffer
  __shared__ float pads[32];
  constexpr int MT = (LSEQ + 15) / 16;             // query/key 16-tiles
  const int blk = blockIdx.x;
  const int tid = threadIdx.x;
  const int w = tid >> 6, lane = tid & 63;
  const int quad = lane >> 4, l16 = lane & 15;
  ushort* base = qkv + (size_t)blk * LSEQ * 768;
  const uint4* src = (const uint4*)base;
  const uint4 z4 = {0u, 0u, 0u, 0u};

  // zero Qs/Ks pad rows (LSEQ..31)
  for (int i = tid; i < (32 - LSEQ) * 32 * 2; i += 256) {
    int arr = (i >= (32 - LSEQ) * 32);
    int rem = arr ? i - (32 - LSEQ) * 32 : i;
    int row = LSEQ + (rem >> 5), ch = rem & 31;
    *(uint4*)&((arr ? Ks : Qs)[row * 256 + ch * 8]) = z4;
  }
  // zero Vt pad key-octets (swizzled position per row)
  for (int i = tid; i < 256 * (4 - LSEQ / 8); i += 256) {
    int row = i & 255, pc = LSEQ / 8 + (i >> 8);
    *(uint4*)&Vt[row * 32 + ((pc ^ ((row >> 3) & 3)) * 8)] = z4;
  }
  // zero this wave's Ps (wave-local; covers never-written positions)
  {
    ushort* pz = Ps + w * 1024;
    *(uint4*)&pz[lane * 16] = z4;
    *(uint4*)&pz[lane * 16 + 8] = z4;
  }
  if (tid < 32) {
    float pv = 1.f;
    if (tid < LSEQ) pv = MASKED ? ((inputs[blk * LSEQ + tid] == 0) ? 1.f : 0.f) : 0.f;
    pads[tid] = pv;
  }
  // load q/k (chunk-swizzled) and v (transposed)
  for (int i = tid; i < LSEQ * 96; i += 256) {
    int c = i / 96, part = i % 96;
    uint4 val = src[c * 96 + part];
    int sect = part >> 5, off = part & 31;
    if (sect == 0) {
      *(uint4*)&Qs[c * 256 + ((off ^ (c & 7)) * 8)] = val;
    } else if (sect == 1) {
      *(uint4*)&Ks[c * 256 + ((off ^ (c & 7)) * 8)] = val;
    } else {
      int d0 = (off & 31) * 8;
      const ushort* us = (const ushort*)&val;
#pragma unroll
      for (int j = 0; j < 8; j++) {
        int dim = d0 + j;
        Vt[dim * 32 + (((c >> 3) ^ ((dim >> 3) & 3)) * 8) + (c & 7)] = us[j];
      }
    }
  }
  __syncthreads();

  ushort* Psw = Ps + w * 1024;
#pragma unroll
  for (int t = 0; t < 2; t++) {
    const int h = w * 2 + t, hb = h * 32;
    shortx8 aq[MT], bk[MT];
#pragma unroll
    for (int i = 0; i < MT; i++)
      aq[i] = *(const shortx8*)&Qs[(i * 16 + l16) * 256 + (((h * 4 + quad) ^ (l16 & 7)) * 8)];
#pragma unroll
    for (int j = 0; j < MT; j++)
      bk[j] = *(const shortx8*)&Ks[(j * 16 + l16) * 256 + (((h * 4 + quad) ^ (l16 & 7)) * 8)];
    floatx4 s[MT][MT];
#pragma unroll
    for (int i = 0; i < MT; i++)
#pragma unroll
      for (int j = 0; j < MT; j++) {
        floatx4 zz = {0.f, 0.f, 0.f, 0.f};
        s[i][j] = __builtin_amdgcn_mfma_f32_16x16x32_bf16(aq[i], bk[j], zz, 0, 0, 0);
      }
    float pv[MT];
#pragma unroll
    for (int j = 0; j < MT; j++) pv[j] = pads[j * 16 + l16];
#pragma unroll
    for (int i = 0; i < MT; i++) {
#pragma unroll
      for (int r = 0; r < 4; r++) {
        float v[MT];
        float mx = -3e38f;
#pragma unroll
        for (int j = 0; j < MT; j++) {
          float x = s[i][j][r] * 0.17677669529663687f;
          if (pv[j] != 0.f) x = -1e9f;
          v[j] = x;
          mx = fmaxf(mx, x);
        }
#pragma unroll
        for (int off = 1; off < 16; off <<= 1) mx = fmaxf(mx, __shfl_xor(mx, off));
        float den = 0.f;
#pragma unroll
        for (int j = 0; j < MT; j++) { v[j] = __expf(v[j] - mx); den += v[j]; }
#pragma unroll
        for (int off = 1; off < 16; off <<= 1) den += __shfl_xor(den, off);
        float inv = 1.f / den;
        int row = i * 16 + quad * 4 + r;
#pragma unroll
        for (int j = 0; j < MT; j++) {
          int col = j * 16 + l16;
          Psw[row * 32 + (((col >> 3) ^ ((row >> 1) & 3)) * 8) + (col & 7)] = f2bf(v[j] * inv);
        }
      }
    }
    WAIT_LGKM0();   // wave-local Ps writes complete before A-frag reads
    shortx8 pa[MT], bv[2];
#pragma unroll
    for (int i = 0; i < MT; i++) {
      int row = i * 16 + l16;
      pa[i] = *(const shortx8*)&Psw[row * 32 + ((quad ^ ((row >> 1) & 3)) * 8)];
    }
#pragma unroll
    for (int jj = 0; jj < 2; jj++) {
      int row = hb + jj * 16 + l16;
      bv[jj] = *(const shortx8*)&Vt[row * 32 + ((quad ^ ((row >> 3) & 3)) * 8)];
    }
    floatx4 o[MT][2];
#pragma unroll
    for (int i = 0; i < MT; i++)
#pragma unroll
      for (int jj = 0; jj < 2; jj++) {
        floatx4 zz = {0.f, 0.f, 0.f, 0.f};
        o[i][jj] = __builtin_amdgcn_mfma_f32_16x16x32_bf16(pa[i], bv[jj], zz, 0, 0, 0);
      }
#pragma unroll
    for (int i = 0; i < MT; i++)
#pragma unroll
      for (int r = 0; r < 4; r++) {
        int row = i * 16 + quad * 4 + r;
        if (row < LSEQ) {
#pragma unroll
          for (int jj = 0; jj < 2; jj++)
            base[(size_t)row * 768 + hb + jj * 16 + l16] = f2bf(o[i][jj][r]);
        }
      }
  }
}

// ---------------- masked mean over chars -> scatter into padded + flag real slots
__global__ __launch_bounds__(256) void pool_scatter(const ushort* __restrict__ ft,
                                                    const int* __restrict__ inputs,
                                                    const int* __restrict__ cid,
                                                    const int* __restrict__ wpos,
                                                    ushort* __restrict__ padded,
                                                    int* __restrict__ flags) {
  int w = blockIdx.x, d = threadIdx.x;
  float s = 0.f;
  int cnt = 0;
  for (int c = 0; c < LW; c++) {
    if (inputs[w * LW + c] != 0) {
      s += bf2f(ft[((size_t)w * LW + c) * DIM + d]);
      cnt++;
    }
  }
  int slot = cid[w] * MAXW + wpos[w];
  padded[(size_t)slot * DIM + d] = f2bf(s / (float)cnt);
  if (d == 0) flags[slot] = 1;
}

// ---------------- final: mean over real word rows per concept -> f32 out
__global__ __launch_bounds__(256) void final_pool(const ushort* __restrict__ nft,
                                                  const int* __restrict__ flags,
                                                  float* __restrict__ out) {
  int n = blockIdx.x, d = threadIdx.x;
  float s = 0.f;
  int cnt = 0;
  for (int wd = 0; wd < MAXW; wd++) {
    if (flags[n * MAXW + wd]) {
      s += bf2f(nft[((size_t)n * MAXW + wd) * DIM + d]);
      cnt++;
    }
  }
  out[n * DIM + d] = s / (float)cnt;
}

extern "C" void kernel_launch(void* const* d_in, const int* in_sizes, int n_in,
                              void* d_out, int out_size, void* d_ws, size_t ws_size,
                              hipStream_t stream) {
  const int* inputs = (const int*)d_in[0];
  const int* cid = (const int*)d_in[1];
  const int* wpos = (const int*)d_in[2];
  const float* we_emb = (const float*)d_in[5];
  const float* we_qkv = (const float*)d_in[6];
  const float* we_o = (const float*)d_in[7];
  const float* we_ff1 = (const float*)d_in[8];
  const float* we_ff2 = (const float*)d_in[9];
  const float* ne_qkv = (const float*)d_in[10];
  const float* ne_o = (const float*)d_in[11];
  const float* ne_ff1 = (const float*)d_in[12];
  const float* ne_ff2 = (const float*)d_in[13];
  float* out = (float*)d_out;

  int chunks = 4;
  if (ws_size >= 515000000UL) chunks = 1;
  else if (ws_size >= 263258112UL) chunks = 2;
  const int wpc = NWORDS / chunks;
  const int tpc = wpc * LW;

  const size_t X = (size_t)tpc * DIM * 2;      // x / h size
  const size_t Q = (size_t)tpc * 768 * 2;      // qkv size

  char* base = (char*)d_ws;
  ushort* x = (ushort*)(base);
  ushort* qkv = (ushort*)(base + X);
  ushort* h = (ushort*)(base + X + Q);
  ushort* ft = qkv;                             // qkv dead after o-proj
  size_t pend = X + Q + X;
  ushort* padded = (ushort*)(base + pend);                // 8,388,608 B
  int* flags = (int*)(base + pend + 8388608);             // 65,536 B
  ushort* wT = (ushort*)(base + pend + 8454144);          // 3,145,728 B
  // name-stage buffers alias the word-stage region (dead by then)
  ushort* nqkv = (ushort*)(base);                         // 25,165,824
  ushort* nh = (ushort*)(base + 25165824);                // 8,388,608
  ushort* nft = (ushort*)(base + 33554432);               // 8,388,608

  ushort* wqkvT = wT;
  ushort* woT = wT + 196608;
  ushort* wff1T = wT + 262144;
  ushort* wff2T = wT + 524288;
  ushort* nqkvT = wT + 786432;
  ushort* neoT = wT + 983040;
  ushort* neff1T = wT + 1048576;
  ushort* neff2T = wT + 1310720;

  // single launch for all 8 weight transposes
  {
    WPAll a;
    a.seg[0] = {we_qkv, wqkvT, 256, 768, 0};
    a.seg[1] = {we_o, woT, 256, 256, 768};
    a.seg[2] = {we_ff1, wff1T, 256, 1024, 1024};
    a.seg[3] = {we_ff2, wff2T, 1024, 256, 2048};
    a.seg[4] = {ne_qkv, nqkvT, 256, 768, 3072};
    a.seg[5] = {ne_o, neoT, 256, 256, 3840};
    a.seg[6] = {ne_ff1, neff1T, 256, 1024, 4096};
    a.seg[7] = {ne_ff2, neff2T, 1024, 256, 5120};
    wprep_all<<<6144, 256, 0, stream>>>(a, 8);
  }

  (void)hipMemsetAsync(padded, 0, (size_t)TN * DIM * 2, stream);
  (void)hipMemsetAsync(flags, 0, TN * 4, stream);

  for (int c = 0; c < chunks; c++) {
    const int* in_c = inputs + (size_t)c * wpc * LW;
    const int* cid_c = cid + (size_t)c * wpc;
    const int* wpos_c = wpos + (size_t)c * wpc;

    embed8<<<tpc / 8, 256, 0, stream>>>(in_c, we_emb, x, tpc);
    // QKV: one block covers all 3 N-tiles (A staged once; was grid (3, M/64))
    {
      dim3 g(1, tpc / 64);
      gemm_tok64<false, 3><<<g, 256, 0, stream>>>(x, 256, wqkvT, nullptr, qkv, 768);
    }
    attn<24, true><<<wpc, 256, 0, stream>>>(in_c, qkv);
    // o-proj + residual(x) + LN -> h   (o lives in the q slot of qkv, lda=768)
    {
      dim3 g(1, tpc / 64);
      gemm_tok64<true, 1><<<g, 256, 0, stream>>>(qkv, 768, woT, x, h, 256);
    }
    ffn_fused<<<tpc / 64, 256, 0, stream>>>(h, wff1T, wff2T, ft, tpc);
    pool_scatter<<<wpc, 256, 0, stream>>>(ft, in_c, cid_c, wpos_c, padded, flags);
  }

  // name-level block
  {
    dim3 g(1, TN / 64);
    gemm_tok64<false, 3><<<g, 256, 0, stream>>>(padded, 256, nqkvT, nullptr, nqkv, 768);
  }
  attn<16, false><<<NCONC, 256, 0, stream>>>(nullptr, nqkv);
  {
    dim3 g(1, TN / 64);
    gemm_tok64<true, 1><<<g, 256, 0, stream>>>(nqkv, 768, neoT, padded, nh, 256);
  }
  ffn_fused<<<TN / 64, 256, 0, stream>>>(nh, neff1T, neff2T, nft, TN);
  final_pool<<<NCONC, 256, 0, stream>>>(nft, flags, out);
}